// Round 3
// baseline (3266.862 us; speedup 1.0000x reference)
//
#include <hip/hip_runtime.h>
#include <hip/hip_bf16.h>
#include <type_traits>

// Problem dims
#define V_    10000
#define ENC_  2048
#define D_    512
#define B_    128
#define L_    64
#define T_    63          // L-1 timesteps
#define M_    (B_ * T_)   // 8064 rows (b*63 + t)
#define G_    (3 * D_)    // 1536 gate width
#define LOGITS_SZ ((long)M_ * V_)   // 80,640,000

typedef __bf16 bf16x8_t __attribute__((ext_vector_type(8)));
typedef float  f32x4_t  __attribute__((ext_vector_type(4)));
typedef short  s16x8_t  __attribute__((ext_vector_type(8)));

__device__ __forceinline__ float bf2f(short s) {
  return __uint_as_float(((unsigned)(unsigned short)s) << 16);
}
__device__ __forceinline__ short f2bf(float f) {
  __hip_bfloat16 h = __float2bfloat16(f);  // RNE
  return *reinterpret_cast<short*>(&h);
}
// load 8 f32, convert to 8 bf16
__device__ __forceinline__ s16x8_t cvt8(const float* p) {
  f32x4_t lo = *reinterpret_cast<const f32x4_t*>(p);
  f32x4_t hi = *reinterpret_cast<const f32x4_t*>(p + 4);
  s16x8_t r;
#pragma unroll
  for (int e = 0; e < 4; e++) { r[e] = f2bf(lo[e]); r[4 + e] = f2bf(hi[e]); }
  return r;
}
__device__ __forceinline__ float sigmoidf_(float x) {
  return 1.0f / (1.0f + __expf(-x));
}

// ---------------- h0 = tanh(gf @ W_init^T + b_init) ----------------
__global__ __launch_bounds__(512) void GG_h0_kernel(
    const float* __restrict__ gf,     // [B][ENC] f32
    const float* __restrict__ Winit,  // [D][ENC] f32
    const float* __restrict__ binit,  // [D] f32
    __hip_bfloat16* __restrict__ h0b) {  // [B][D] bf16
  const int b = blockIdx.x;
  const int j = threadIdx.x;  // 0..511
  __shared__ float gfs[ENC_];
  *reinterpret_cast<f32x4_t*>(&gfs[j * 4]) =
      *reinterpret_cast<const f32x4_t*>(gf + (long)b * ENC_ + j * 4);
  __syncthreads();
  float acc = 0.f;
  const float* w = Winit + (long)j * ENC_;
#pragma unroll 4
  for (int k = 0; k < ENC_; k += 4) {
    f32x4_t wv = *reinterpret_cast<const f32x4_t*>(w + k);
    acc += gfs[k] * wv[0] + gfs[k + 1] * wv[1] + gfs[k + 2] * wv[2] + gfs[k + 3] * wv[3];
  }
  h0b[b * D_ + j] = __float2bfloat16(tanhf(acc + binit[j]));
}

// ---------------- MFMA GEMM (C = A @ Bw^T + bias) ----------------
// 128x128 tile, BK=64, 4 waves (2x2 of 64x64), mfma_f32_16x16x32_bf16.
// Register-staged; f32 sources converted to bf16 during staging.
// GATHER: A rows from W_embed[cap[...]]. NBOUND: clamp/guard N (logits).
// AF32: A source is f32 (else bf16). CF32: C output f32 (else bf16).
template <bool GATHER, bool NBOUND, bool AF32, bool CF32>
__global__ __launch_bounds__(256) void GG_gemm_bt(
    const void* __restrict__ Asrc_,   // GATHER ? W_embed[V][512] : A [M][512]
    const int* __restrict__ cap,      // [B][L] int32 (GATHER only)
    const float* __restrict__ Bw,     // [N][512] f32
    const float* __restrict__ bias,   // [N] f32
    void* __restrict__ C_,            // [M][ldc]
    int N, int ldc) {
  using AT = std::conditional_t<AF32, float, __hip_bfloat16>;
  const AT* Asrc = (const AT*)Asrc_;
  __shared__ short sA[128 * 64];
  __shared__ short sB[128 * 64];
  const int tid = threadIdx.x;
  const int lane = tid & 63;
  const int wave = tid >> 6;
  const int m0 = blockIdx.y * 128;
  const int n0 = blockIdx.x * 128;

  const int srow = lane >> 3;        // row within 8-row chunk
  const int scol = (lane & 7) * 8;   // k-elem offset (8 elems)

  f32x4_t acc[4][4] = {};

  const AT* aptr[4];
  const float* bptr[4];
#pragma unroll
  for (int i = 0; i < 4; i++) {
    const int chunk = wave * 4 + i;  // 0..15
    const int r = chunk * 8 + srow;  // 0..127
    if constexpr (GATHER) {
      const int bt = m0 + r;
      const int bb = bt / 63;
      const int tt = bt - bb * 63;
      const int tok = cap[bb * L_ + tt];
      aptr[i] = Asrc + (long)tok * 512 + scol;
    } else {
      aptr[i] = Asrc + (long)(m0 + r) * 512 + scol;
    }
    int nrow = n0 + r;
    if constexpr (NBOUND) nrow = (nrow < N) ? nrow : (N - 1);
    bptr[i] = Bw + (long)nrow * 512 + scol;
  }

  const int wm = (wave >> 1) * 64;
  const int wn = (wave & 1) * 64;
  const int fr = lane & 15;
  const int fk = (lane >> 4) * 8;

  for (int kt = 0; kt < 8; kt++) {
    // stage: global -> regs (+ f32->bf16 convert)
    s16x8_t va[4], vb[4];
#pragma unroll
    for (int i = 0; i < 4; i++) {
      if constexpr (AF32) va[i] = cvt8(aptr[i] + kt * 64);
      else                va[i] = *reinterpret_cast<const s16x8_t*>(aptr[i] + kt * 64);
      vb[i] = cvt8(bptr[i] + kt * 64);
    }
    __syncthreads();  // previous iter's LDS reads complete
#pragma unroll
    for (int i = 0; i < 4; i++) {
      const int chunk = wave * 4 + i;
      *reinterpret_cast<s16x8_t*>(sA + chunk * 512 + lane * 8) = va[i];
      *reinterpret_cast<s16x8_t*>(sB + chunk * 512 + lane * 8) = vb[i];
    }
    __syncthreads();  // LDS tiles ready
#pragma unroll
    for (int kk = 0; kk < 2; kk++) {
      bf16x8_t a[4], b[4];
#pragma unroll
      for (int i = 0; i < 4; i++) {
        a[i] = __builtin_bit_cast(bf16x8_t,
            *reinterpret_cast<const s16x8_t*>(sA + (wm + i * 16 + fr) * 64 + kk * 32 + fk));
        b[i] = __builtin_bit_cast(bf16x8_t,
            *reinterpret_cast<const s16x8_t*>(sB + (wn + i * 16 + fr) * 64 + kk * 32 + fk));
      }
#pragma unroll
      for (int i = 0; i < 4; i++)
#pragma unroll
        for (int j = 0; j < 4; j++)
          acc[i][j] = __builtin_amdgcn_mfma_f32_16x16x32_bf16(a[i], b[j], acc[i][j], 0, 0, 0);
    }
  }

  // Epilogue: bias add, store
  const int fq = lane >> 4;
#pragma unroll
  for (int j = 0; j < 4; j++) {
    const int n = n0 + wn + j * 16 + fr;
    bool nok = true;
    int nc = n;
    if constexpr (NBOUND) { nok = (n < N); nc = nok ? n : (N - 1); }
    const float bv = bias[nc];
#pragma unroll
    for (int i = 0; i < 4; i++) {
#pragma unroll
      for (int rr = 0; rr < 4; rr++) {
        const int m = m0 + wm + i * 16 + fq * 4 + rr;
        const float v = acc[i][j][rr] + bv;
        if (!NBOUND || nok) {
          if constexpr (CF32) ((float*)C_)[(long)m * ldc + n] = v;
          else ((__hip_bfloat16*)C_)[(long)m * ldc + n] = __float2bfloat16(v);
        }
      }
    }
  }
}

// ---------------- GRU scan step (fused gh GEMM + gate update) ----------------
// Block: 16 batch rows x 16 hidden cols; all 3 gates computed locally.
__global__ __launch_bounds__(256) void GG_scan_step(
    int t,
    const __hip_bfloat16* __restrict__ hprev_base,  // row b at base + b*bstride
    long bstride,
    const __hip_bfloat16* __restrict__ gi,  // [M][G] bf16, row b*63+t
    const float* __restrict__ Whh,          // [G][D] f32
    const float* __restrict__ bhh,          // [G] f32
    __hip_bfloat16* __restrict__ hs) {      // [M][D] bf16
  const int r = threadIdx.x >> 4;   // 0..15 row-in-group
  const int c = threadIdx.x & 15;   // 0..15 col-in-slice
  const int b0 = blockIdx.y * 16;
  const int d0 = blockIdx.x * 16;
  const int b = b0 + r;

  __shared__ float hA[16][516];  // padded rows

  // Stage 16 h-rows (bf16 -> f32)
  for (int i = threadIdx.x; i < 16 * 64; i += 256) {
    const int rr = i >> 6;       // row
    const int cc = i & 63;       // chunk of 8
    s16x8_t v = *reinterpret_cast<const s16x8_t*>(hprev_base + (long)(b0 + rr) * bstride + cc * 8);
#pragma unroll
    for (int e = 0; e < 8; e++) hA[rr][cc * 8 + e] = bf2f(v[e]);
  }
  __syncthreads();

  const int g0 = 0 * D_ + d0 + c;
  const int g1 = 1 * D_ + d0 + c;
  const int g2 = 2 * D_ + d0 + c;
  const float* w0 = Whh + (long)g0 * D_;
  const float* w1 = Whh + (long)g1 * D_;
  const float* w2 = Whh + (long)g2 * D_;

  float acc0 = 0.f, acc1 = 0.f, acc2 = 0.f;
#pragma unroll 4
  for (int k = 0; k < D_; k += 4) {
    const f32x4_t hv = *reinterpret_cast<const f32x4_t*>(&hA[r][k]);
    const f32x4_t a0 = *reinterpret_cast<const f32x4_t*>(w0 + k);
    const f32x4_t a1 = *reinterpret_cast<const f32x4_t*>(w1 + k);
    const f32x4_t a2 = *reinterpret_cast<const f32x4_t*>(w2 + k);
#pragma unroll
    for (int e = 0; e < 4; e++) {
      acc0 += hv[e] * a0[e];
      acc1 += hv[e] * a1[e];
      acc2 += hv[e] * a2[e];
    }
  }

  const long girow = ((long)b * T_ + t) * G_;
  const float hr_g = acc0 + bhh[g0];
  const float hz_g = acc1 + bhh[g1];
  const float hn_g = acc2 + bhh[g2];
  const float ir  = bf2f(*(const short*)&gi[girow + g0]);
  const float iz  = bf2f(*(const short*)&gi[girow + g1]);
  const float in_ = bf2f(*(const short*)&gi[girow + g2]);
  const float rg = sigmoidf_(ir + hr_g);
  const float zg = sigmoidf_(iz + hz_g);
  const float ng = tanhf(in_ + rg * hn_g);
  const float hp = hA[r][d0 + c];
  const float hnew = (1.f - zg) * ng + zg * hp;
  hs[((long)b * T_ + t) * D_ + d0 + c] = __float2bfloat16(hnew);
}

// ---------------- tail: out[LOGITS_SZ + b] = f32(len[b] - 1) ----------------
__global__ void GG_tail_kernel(const int* __restrict__ lens, float* __restrict__ out) {
  const int b = threadIdx.x;
  if (b < B_) out[LOGITS_SZ + b] = (float)(lens[b] - 1);
}

extern "C" void kernel_launch(void* const* d_in, const int* in_sizes, int n_in,
                              void* d_out, int out_size, void* d_ws, size_t ws_size,
                              hipStream_t stream) {
  const float* gf      = (const float*)d_in[0];
  const int*   cap     = (const int*)d_in[1];
  const int*   lens    = (const int*)d_in[2];
  const float* W_embed = (const float*)d_in[3];
  const float* W_init  = (const float*)d_in[4];
  const float* b_init  = (const float*)d_in[5];
  const float* W_ih    = (const float*)d_in[6];
  const float* W_hh    = (const float*)d_in[7];
  const float* b_ih    = (const float*)d_in[8];
  const float* b_hh    = (const float*)d_in[9];
  const float* W_fc    = (const float*)d_in[10];
  const float* b_fc    = (const float*)d_in[11];
  float* out = (float*)d_out;

  // gi (bf16) lives in d_out scratch bytes: consumed by the scan BEFORE the
  // logits GEMM overwrites the region (same-stream ordering).
  // M*G bf16 = 24.8 MB << 322.6 MB f32 output buffer.
  __hip_bfloat16* gi_ws = (__hip_bfloat16*)d_out;

  // ws: hs (M*D bf16 = 8,257,536 B) + h0 (B*D bf16 = 131,072 B) = 8.4 MB
  char* ws = (char*)d_ws;
  __hip_bfloat16* hs_ws  = (__hip_bfloat16*)(ws);
  __hip_bfloat16* h0b_ws = (__hip_bfloat16*)(ws + 8257536);

  // 1. h0 (f32 compute, bf16 store)
  GG_h0_kernel<<<dim3(B_), 512, 0, stream>>>(gf, W_init, b_init, h0b_ws);

  // 2. gi = gather(W_embed, cap) @ W_ih^T + b_ih  (A f32 gather, C bf16)
  GG_gemm_bt<true, false, true, false><<<dim3(G_ / 128, M_ / 128), 256, 0, stream>>>(
      W_embed, cap, W_ih, b_ih, gi_ws, G_, G_);

  // 3. GRU scan: 63 sequential fused steps (f32 Whh, f32 accum)
  for (int t = 0; t < T_; t++) {
    const __hip_bfloat16* hp = (t == 0) ? h0b_ws : (hs_ws + (long)(t - 1) * D_);
    const long bstride = (t == 0) ? (long)D_ : (long)T_ * D_;
    GG_scan_step<<<dim3(D_ / 16, B_ / 16), 256, 0, stream>>>(
        t, hp, bstride, gi_ws, W_hh, b_hh, hs_ws);
  }

  // 4. logits = hs @ W_fc^T + b_fc  (A bf16, B f32->bf16 staged, C f32)
  GG_gemm_bt<false, true, false, true><<<dim3((V_ + 127) / 128, M_ / 128), 256, 0, stream>>>(
      hs_ws, nullptr, W_fc, b_fc, out, V_, V_);

  // 5. second output: caption_lengths - 1 (f32)
  GG_tail_kernel<<<dim3(1), 128, 0, stream>>>(lens, out);
}

// Round 4
// 1105.535 us; speedup vs baseline: 2.9550x; 2.9550x over previous
//
#include <hip/hip_runtime.h>
#include <hip/hip_bf16.h>
#include <type_traits>

// Problem dims
#define V_    10000
#define ENC_  2048
#define D_    512
#define B_    128
#define L_    64
#define T_    63          // L-1 timesteps
#define M_    (B_ * T_)   // 8064 rows (b*63 + t)
#define G_    (3 * D_)    // 1536 gate width
#define LOGITS_SZ ((long)M_ * V_)   // 80,640,000

typedef __bf16 bf16x8_t __attribute__((ext_vector_type(8)));
typedef float  f32x4_t  __attribute__((ext_vector_type(4)));
typedef short  s16x8_t  __attribute__((ext_vector_type(8)));

typedef __attribute__((address_space(3))) char*       lds_cptr_t;
typedef const __attribute__((address_space(1))) char* glb_cptr_t;

// wave-uniform LDS dest; HW writes lane l at dest + l*16
__device__ __forceinline__ void gload_lds16(const void* g, void* l) {
  __builtin_amdgcn_global_load_lds((glb_cptr_t)g, (lds_cptr_t)l, 16, 0, 0);
}
__device__ __forceinline__ float bf2f(short s) {
  return __uint_as_float(((unsigned)(unsigned short)s) << 16);
}
__device__ __forceinline__ short f2bf(float f) {
  __hip_bfloat16 h = __float2bfloat16(f);  // RNE
  return *reinterpret_cast<short*>(&h);
}
__device__ __forceinline__ s16x8_t cvt8(const float* p) {
  f32x4_t lo = *reinterpret_cast<const f32x4_t*>(p);
  f32x4_t hi = *reinterpret_cast<const f32x4_t*>(p + 4);
  s16x8_t r;
#pragma unroll
  for (int e = 0; e < 4; e++) { r[e] = f2bf(lo[e]); r[4 + e] = f2bf(hi[e]); }
  return r;
}
__device__ __forceinline__ float sigmoidf_(float x) {
  return 1.0f / (1.0f + __expf(-x));
}
__device__ __forceinline__ bf16x8_t lds_frag(const short* p) {
  return __builtin_bit_cast(bf16x8_t, *reinterpret_cast<const s16x8_t*>(p));
}

// ---------------- f32 -> bf16 bulk convert ----------------
__global__ void GG_cvt_kernel(const float* __restrict__ src,
                              __hip_bfloat16* __restrict__ dst, int n8) {
  int i = blockIdx.x * blockDim.x + threadIdx.x;
  if (i < n8) {
    s16x8_t v = cvt8(src + (long)i * 8);
    *reinterpret_cast<s16x8_t*>(dst + (long)i * 8) = v;
  }
}

// ---------------- h0 = tanh(gf @ W_init^T + b_init) -> hfull[b][0][:] ----------------
__global__ __launch_bounds__(512) void GG_h0_kernel(
    const float* __restrict__ gf,     // [B][ENC] f32
    const float* __restrict__ Winit,  // [D][ENC] f32
    const float* __restrict__ binit,  // [D] f32
    __hip_bfloat16* __restrict__ hfull) {  // [B][64][512]
  const int b = blockIdx.x;
  const int j = threadIdx.x;  // 0..511
  __shared__ float gfs[ENC_];
  *reinterpret_cast<f32x4_t*>(&gfs[j * 4]) =
      *reinterpret_cast<const f32x4_t*>(gf + (long)b * ENC_ + j * 4);
  __syncthreads();
  float acc = 0.f;
  const float* w = Winit + (long)j * ENC_;
#pragma unroll 4
  for (int k = 0; k < ENC_; k += 4) {
    f32x4_t wv = *reinterpret_cast<const f32x4_t*>(w + k);
    acc += gfs[k] * wv[0] + gfs[k + 1] * wv[1] + gfs[k + 2] * wv[2] + gfs[k + 3] * wv[3];
  }
  hfull[((long)b * 64) * 512 + j] = __float2bfloat16(tanhf(acc + binit[j]));
}

// ---------------- gi GEMM: gi = gather(W_embed,cap) @ W_ih^T + b_ih ----------------
// A: f32 gather (reg-staged + cvt), B: bf16 via global_load_lds. C bf16.
// grid (12, 63), 128x128 tile, BK=64.
__global__ __launch_bounds__(256) void GG_gemm_gi(
    const float* __restrict__ Wembed,          // [V][512] f32
    const int* __restrict__ cap,               // [B][L] int32
    const __hip_bfloat16* __restrict__ WihB,   // [G][512] bf16
    const float* __restrict__ bias,            // [G] f32
    __hip_bfloat16* __restrict__ C) {          // [M][G]
  __shared__ short sA[128 * 64];
  __shared__ short sB[128 * 64];
  const int lane = threadIdx.x & 63;
  const int wave = threadIdx.x >> 6;
  const int m0 = blockIdx.y * 128;
  const int n0 = blockIdx.x * 128;
  const int srow = lane >> 3;
  const int scol = (lane & 7) * 8;

  f32x4_t acc[4][4] = {};

  const float* aptr[4];
  const __hip_bfloat16* bptr[4];
#pragma unroll
  for (int i = 0; i < 4; i++) {
    const int r = (wave * 4 + i) * 8 + srow;
    const int bt = m0 + r;
    const int bb = bt / 63;
    const int tt = bt - bb * 63;
    aptr[i] = Wembed + (long)cap[bb * L_ + tt] * 512 + scol;
    bptr[i] = WihB + (long)(n0 + r) * 512 + scol;
  }

  const int wm = (wave >> 1) * 64;
  const int wn = (wave & 1) * 64;
  const int fr = lane & 15;
  const int fk = (lane >> 4) * 8;

  for (int kt = 0; kt < 8; kt++) {
    s16x8_t va[4];
#pragma unroll
    for (int i = 0; i < 4; i++) va[i] = cvt8(aptr[i] + kt * 64);
    __syncthreads();
#pragma unroll
    for (int i = 0; i < 4; i++) {
      const int chunk = wave * 4 + i;
      *reinterpret_cast<s16x8_t*>(sA + chunk * 512 + lane * 8) = va[i];
      gload_lds16(bptr[i] + kt * 64, sB + chunk * 512);
    }
    __syncthreads();
#pragma unroll
    for (int kk = 0; kk < 2; kk++) {
      bf16x8_t a[4], b[4];
#pragma unroll
      for (int i = 0; i < 4; i++) {
        a[i] = lds_frag(sA + (wm + i * 16 + fr) * 64 + kk * 32 + fk);
        b[i] = lds_frag(sB + (wn + i * 16 + fr) * 64 + kk * 32 + fk);
      }
#pragma unroll
      for (int i = 0; i < 4; i++)
#pragma unroll
        for (int j = 0; j < 4; j++)
          acc[i][j] = __builtin_amdgcn_mfma_f32_16x16x32_bf16(a[i], b[j], acc[i][j], 0, 0, 0);
    }
  }

  const int fq = lane >> 4;
#pragma unroll
  for (int j = 0; j < 4; j++) {
    const int n = n0 + wn + j * 16 + fr;
    const float bv = bias[n];
#pragma unroll
    for (int i = 0; i < 4; i++)
#pragma unroll
      for (int rr = 0; rr < 4; rr++) {
        const int m = m0 + wm + i * 16 + fq * 4 + rr;
        C[(long)m * G_ + n] = __float2bfloat16(acc[i][j][rr] + bv);
      }
  }
}

// ---------------- logits GEMM: logits = hs @ W_fc^T + b_fc ----------------
// A: hfull bf16 (row m -> b*64+t+1), B: bf16 (gload) or f32 (reg-cvt fallback).
// 1D grid 5040 = 8 xcd * 10 colband * 63 rows; xcd owns fixed col band (L2 reuse).
template <bool BBF16>
__global__ __launch_bounds__(256) void GG_gemm_logits(
    const __hip_bfloat16* __restrict__ hfull,  // [B][64][512]
    const void* __restrict__ Bsrc,             // W_fc bf16 or f32 [V][512]
    const float* __restrict__ bias,            // [V] f32
    float* __restrict__ C) {                   // [M][V]
  const int flat = blockIdx.x;
  const int xcd = flat & 7;
  const int s = flat >> 3;           // 0..629
  const int col = xcd * 10 + s % 10; // 0..79
  const int row = s / 10;            // 0..62
  if (col >= 79) return;
  const int m0 = row * 128;
  const int n0 = col * 128;

  __shared__ short sA[128 * 64];
  __shared__ short sB[128 * 64];
  const int lane = threadIdx.x & 63;
  const int wave = threadIdx.x >> 6;
  const int srow = lane >> 3;
  const int scol = (lane & 7) * 8;

  f32x4_t acc[4][4] = {};

  const __hip_bfloat16* aptr[4];
  const __hip_bfloat16* bptrB[4];
  const float* bptrF[4];
#pragma unroll
  for (int i = 0; i < 4; i++) {
    const int r = (wave * 4 + i) * 8 + srow;
    const int m = m0 + r;
    const int bb = m / 63;
    const int tt = m - bb * 63;
    aptr[i] = hfull + ((long)bb * 64 + tt + 1) * 512 + scol;
    int nrow = n0 + r;
    nrow = (nrow < V_) ? nrow : (V_ - 1);
    if constexpr (BBF16) bptrB[i] = (const __hip_bfloat16*)Bsrc + (long)nrow * 512 + scol;
    else                 bptrF[i] = (const float*)Bsrc + (long)nrow * 512 + scol;
  }

  const int wm = (wave >> 1) * 64;
  const int wn = (wave & 1) * 64;
  const int fr = lane & 15;
  const int fk = (lane >> 4) * 8;

  for (int kt = 0; kt < 8; kt++) {
    s16x8_t vb[4];
    if constexpr (!BBF16) {
#pragma unroll
      for (int i = 0; i < 4; i++) vb[i] = cvt8(bptrF[i] + kt * 64);
    }
    __syncthreads();
#pragma unroll
    for (int i = 0; i < 4; i++) {
      const int chunk = wave * 4 + i;
      gload_lds16(aptr[i] + kt * 64, sA + chunk * 512);
      if constexpr (BBF16)
        gload_lds16(bptrB[i] + kt * 64, sB + chunk * 512);
      else
        *reinterpret_cast<s16x8_t*>(sB + chunk * 512 + lane * 8) = vb[i];
    }
    __syncthreads();
#pragma unroll
    for (int kk = 0; kk < 2; kk++) {
      bf16x8_t a[4], b[4];
#pragma unroll
      for (int i = 0; i < 4; i++) {
        a[i] = lds_frag(sA + (wm + i * 16 + fr) * 64 + kk * 32 + fk);
        b[i] = lds_frag(sB + (wn + i * 16 + fr) * 64 + kk * 32 + fk);
      }
#pragma unroll
      for (int i = 0; i < 4; i++)
#pragma unroll
        for (int j = 0; j < 4; j++)
          acc[i][j] = __builtin_amdgcn_mfma_f32_16x16x32_bf16(a[i], b[j], acc[i][j], 0, 0, 0);
    }
  }

  const int fq = lane >> 4;
#pragma unroll
  for (int j = 0; j < 4; j++) {
    const int n = n0 + wn + j * 16 + fr;
    if (n >= V_) continue;
    const float bv = bias[n];
#pragma unroll
    for (int i = 0; i < 4; i++)
#pragma unroll
      for (int rr = 0; rr < 4; rr++) {
        const int m = m0 + wm + i * 16 + fq * 4 + rr;
        C[(long)m * V_ + n] = acc[i][j][rr] + bv;
      }
  }
}

// ---------------- fused MFMA scan step ----------------
// Block owns 16-wide d-strip: B-tile rows 0-15=gate r, 16-31=z, 32-47=n.
// gh = h_{t-1} @ Whh^T for those 48 gate rows, gates fused in epilogue.
// grid 32 blocks x 256 thr; wave w owns batch rows [w*32, w*32+32).
__global__ __launch_bounds__(256) void GG_scan_mfma(
    int t,
    __hip_bfloat16* __restrict__ hfull,       // [B][64][512]
    const __hip_bfloat16* __restrict__ gi,    // [M][G]
    const __hip_bfloat16* __restrict__ WhhB,  // [G][512] bf16
    const float* __restrict__ bhh) {          // [G] f32
  __shared__ short sA[128 * 64];  // h tile
  __shared__ short sB[48 * 64];   // Whh strip tile
  const int lane = threadIdx.x & 63;
  const int wave = threadIdx.x >> 6;
  const int d0 = blockIdx.x * 16;
  const int srow = lane >> 3;
  const int scol = (lane & 7) * 8;

  f32x4_t acc[2][3] = {};
  const int fr = lane & 15;
  const int fk = (lane >> 4) * 8;

  for (int kt = 0; kt < 8; kt++) {
    __syncthreads();
#pragma unroll
    for (int c = wave; c < 22; c += 4) {
      if (c < 16) {
        const int b = c * 8 + srow;
        gload_lds16(hfull + ((long)b * 64 + t) * 512 + kt * 64 + scol, sA + c * 512);
      } else {
        const int tr = (c - 16) * 8 + srow;            // 0..47
        const int grow = (tr >> 4) * 512 + d0 + (tr & 15);
        gload_lds16(WhhB + (long)grow * 512 + kt * 64 + scol, sB + (c - 16) * 512);
      }
    }
    __syncthreads();
#pragma unroll
    for (int kk = 0; kk < 2; kk++) {
      bf16x8_t b[3], a[2];
#pragma unroll
      for (int j = 0; j < 3; j++) b[j] = lds_frag(sB + (j * 16 + fr) * 64 + kk * 32 + fk);
#pragma unroll
      for (int i = 0; i < 2; i++) a[i] = lds_frag(sA + (wave * 32 + i * 16 + fr) * 64 + kk * 32 + fk);
#pragma unroll
      for (int i = 0; i < 2; i++)
#pragma unroll
        for (int j = 0; j < 3; j++)
          acc[i][j] = __builtin_amdgcn_mfma_f32_16x16x32_bf16(a[i], b[j], acc[i][j], 0, 0, 0);
    }
  }

  // epilogue: fused gates
  const int fq = lane >> 4;
  const int dd = d0 + fr;
  const float br_ = bhh[dd];
  const float bz_ = bhh[512 + dd];
  const float bn_ = bhh[1024 + dd];
  const short* gis = (const short*)gi;
#pragma unroll
  for (int i = 0; i < 2; i++) {
#pragma unroll
    for (int rr = 0; rr < 4; rr++) {
      const int b = wave * 32 + i * 16 + fq * 4 + rr;
      const long gbase = ((long)b * T_ + t) * G_;
      const float ir  = bf2f(gis[gbase + dd]);
      const float iz  = bf2f(gis[gbase + 512 + dd]);
      const float in_ = bf2f(gis[gbase + 1024 + dd]);
      const float rg = sigmoidf_(ir + acc[i][0][rr] + br_);
      const float zg = sigmoidf_(iz + acc[i][1][rr] + bz_);
      const float ng = tanhf(in_ + rg * (acc[i][2][rr] + bn_));
      const float hp = bf2f(*(const short*)&hfull[((long)b * 64 + t) * 512 + dd]);
      hfull[((long)b * 64 + t + 1) * 512 + dd] = __float2bfloat16((1.f - zg) * ng + zg * hp);
    }
  }
}

// ---------------- tail: out[LOGITS_SZ + b] = f32(len[b] - 1) ----------------
__global__ void GG_tail_kernel(const int* __restrict__ lens, float* __restrict__ out) {
  const int b = threadIdx.x;
  if (b < B_) out[LOGITS_SZ + b] = (float)(lens[b] - 1);
}

extern "C" void kernel_launch(void* const* d_in, const int* in_sizes, int n_in,
                              void* d_out, int out_size, void* d_ws, size_t ws_size,
                              hipStream_t stream) {
  const float* gf      = (const float*)d_in[0];
  const int*   cap     = (const int*)d_in[1];
  const int*   lens    = (const int*)d_in[2];
  const float* W_embed = (const float*)d_in[3];
  const float* W_init  = (const float*)d_in[4];
  const float* b_init  = (const float*)d_in[5];
  const float* W_ih    = (const float*)d_in[6];
  const float* W_hh    = (const float*)d_in[7];
  const float* b_ih    = (const float*)d_in[8];
  const float* b_hh    = (const float*)d_in[9];
  const float* W_fc    = (const float*)d_in[10];
  const float* b_fc    = (const float*)d_in[11];
  float* out = (float*)d_out;

  // d_out scratch (all consumed before the logits GEMM writes d_out):
  //   [0, 24,772,608)           gi bf16 [M][G]
  //   [25,165,824, 26,738,688)  Whh bf16
  //   [27,262,976, 28,835,840)  W_ih bf16
  char* ob = (char*)d_out;
  __hip_bfloat16* gi_ws = (__hip_bfloat16*)ob;
  __hip_bfloat16* WhhB  = (__hip_bfloat16*)(ob + 25165824);
  __hip_bfloat16* WihB  = (__hip_bfloat16*)(ob + 27262976);

  // ws: hfull [B][64][512] bf16 = 8,388,608 B (slot 0 = h0, slot t+1 = h_t)
  //     + optional W_fc bf16 copy (10,240,000 B) if ws_size allows
  __hip_bfloat16* hfull = (__hip_bfloat16*)d_ws;
  __hip_bfloat16* WfcB  = (__hip_bfloat16*)((char*)d_ws + 8388608);
  const bool big_ws = ws_size >= (size_t)(8388608 + 10240000);

  // 1. weight converts
  GG_cvt_kernel<<<dim3((G_ * D_ / 8 + 255) / 256), 256, 0, stream>>>(W_hh, WhhB, G_ * D_ / 8);
  GG_cvt_kernel<<<dim3((G_ * D_ / 8 + 255) / 256), 256, 0, stream>>>(W_ih, WihB, G_ * D_ / 8);
  if (big_ws)
    GG_cvt_kernel<<<dim3((V_ * D_ / 8 + 255) / 256), 256, 0, stream>>>(W_fc, WfcB, V_ * D_ / 8);

  // 2. h0 -> hfull slot 0
  GG_h0_kernel<<<dim3(B_), 512, 0, stream>>>(gf, W_init, b_init, hfull);

  // 3. gi = gather(W_embed, cap) @ W_ih^T + b_ih
  GG_gemm_gi<<<dim3(G_ / 128, M_ / 128), 256, 0, stream>>>(W_embed, cap, WihB, b_ih, gi_ws);

  // 4. GRU scan: 63 fused MFMA steps
  for (int t = 0; t < T_; t++)
    GG_scan_mfma<<<dim3(D_ / 16), 256, 0, stream>>>(t, hfull, gi_ws, WhhB, b_hh);

  // 5. logits (XCD-banded swizzle, 5040 = 8*10*63 padded blocks)
  if (big_ws)
    GG_gemm_logits<true><<<dim3(5040), 256, 0, stream>>>(hfull, WfcB, b_fc, out);
  else
    GG_gemm_logits<false><<<dim3(5040), 256, 0, stream>>>(hfull, W_fc, b_fc, out);

  // 6. second output
  GG_tail_kernel<<<dim3(1), 128, 0, stream>>>(lens, out);
}

// Round 5
// 910.638 us; speedup vs baseline: 3.5874x; 1.2140x over previous
//
#include <hip/hip_runtime.h>
#include <hip/hip_bf16.h>

// Problem dims
#define V_    10000
#define ENC_  2048
#define D_    512
#define B_    128
#define L_    64
#define T_    63          // L-1 timesteps
#define M_    (B_ * T_)   // 8064 rows (b*63 + t)
#define G_    (3 * D_)    // 1536 gate width
#define LOGITS_SZ ((long)M_ * V_)   // 80,640,000
#define SCAN_NB 32

typedef __bf16 bf16x8_t __attribute__((ext_vector_type(8)));
typedef float  f32x4_t  __attribute__((ext_vector_type(4)));
typedef short  s16x8_t  __attribute__((ext_vector_type(8)));

typedef __attribute__((address_space(3))) char*       lds_cptr_t;
typedef const __attribute__((address_space(1))) char* glb_cptr_t;

// wave-uniform LDS dest; HW writes lane l at dest + l*16B. Global src is per-lane.
__device__ __forceinline__ void gload_lds16(const void* g, void* l) {
  __builtin_amdgcn_global_load_lds((glb_cptr_t)g, (lds_cptr_t)l, 16, 0, 0);
}
__device__ __forceinline__ float bf2f(short s) {
  return __uint_as_float(((unsigned)(unsigned short)s) << 16);
}
__device__ __forceinline__ short f2bf(float f) {
  __hip_bfloat16 h = __float2bfloat16(f);  // RNE
  return *reinterpret_cast<short*>(&h);
}
__device__ __forceinline__ s16x8_t cvt8(const float* p) {
  f32x4_t lo = *reinterpret_cast<const f32x4_t*>(p);
  f32x4_t hi = *reinterpret_cast<const f32x4_t*>(p + 4);
  s16x8_t r;
#pragma unroll
  for (int e = 0; e < 4; e++) { r[e] = f2bf(lo[e]); r[4 + e] = f2bf(hi[e]); }
  return r;
}
__device__ __forceinline__ float sigmoidf_(float x) {
  return 1.0f / (1.0f + __expf(-x));
}
__device__ __forceinline__ bf16x8_t lds_frag(const short* p) {
  return __builtin_bit_cast(bf16x8_t, *reinterpret_cast<const s16x8_t*>(p));
}

// ---------------- f32 -> bf16 bulk convert ----------------
__global__ void GG_cvt_kernel(const float* __restrict__ src,
                              __hip_bfloat16* __restrict__ dst, int n8) {
  int i = blockIdx.x * blockDim.x + threadIdx.x;
  if (i < n8) {
    s16x8_t v = cvt8(src + (long)i * 8);
    *reinterpret_cast<s16x8_t*>(dst + (long)i * 8) = v;
  }
}

// ---------------- h0 GEMM: hfull[b][0][:] = tanh(gf @ W_init^T + b_init) ----------------
// M=128, N=512 (grid 4 x n-tiles), K=2048 (KTILES=32). Both operands bf16 via gload.
__global__ __launch_bounds__(256) void GG_gemm_h0(
    const __hip_bfloat16* __restrict__ gfB,     // [128][2048] bf16
    const __hip_bfloat16* __restrict__ WinitB,  // [512][2048] bf16
    const float* __restrict__ binit,            // [512] f32
    __hip_bfloat16* __restrict__ hfull) {       // [B][64][512]
  __shared__ short sA[128 * 64];
  __shared__ short sB[128 * 64];
  const int lane = threadIdx.x & 63;
  const int wave = threadIdx.x >> 6;
  const int n0 = blockIdx.x * 128;
  const int srow = lane >> 3;
  const int scol = (lane & 7) * 8;

  f32x4_t acc[4][4] = {};

  const __hip_bfloat16* aptr[4];
  const __hip_bfloat16* bptr[4];
#pragma unroll
  for (int i = 0; i < 4; i++) {
    const int r = (wave * 4 + i) * 8 + srow;
    aptr[i] = gfB + (long)r * ENC_ + scol;
    bptr[i] = WinitB + (long)(n0 + r) * ENC_ + scol;
  }

  const int wm = (wave >> 1) * 64;
  const int wn = (wave & 1) * 64;
  const int fr = lane & 15;
  const int fk = (lane >> 4) * 8;

  for (int kt = 0; kt < 32; kt++) {
    __syncthreads();
#pragma unroll
    for (int i = 0; i < 4; i++) {
      const int chunk = wave * 4 + i;
      gload_lds16(aptr[i] + kt * 64, sA + chunk * 512);
      gload_lds16(bptr[i] + kt * 64, sB + chunk * 512);
    }
    __syncthreads();
#pragma unroll
    for (int kk = 0; kk < 2; kk++) {
      bf16x8_t a[4], b[4];
#pragma unroll
      for (int i = 0; i < 4; i++) {
        a[i] = lds_frag(sA + (wm + i * 16 + fr) * 64 + kk * 32 + fk);
        b[i] = lds_frag(sB + (wn + i * 16 + fr) * 64 + kk * 32 + fk);
      }
#pragma unroll
      for (int i = 0; i < 4; i++)
#pragma unroll
        for (int j = 0; j < 4; j++)
          acc[i][j] = __builtin_amdgcn_mfma_f32_16x16x32_bf16(a[i], b[j], acc[i][j], 0, 0, 0);
    }
  }

  const int fq = lane >> 4;
#pragma unroll
  for (int j = 0; j < 4; j++) {
    const int n = n0 + wn + j * 16 + fr;
    const float bv = binit[n];
#pragma unroll
    for (int i = 0; i < 4; i++)
#pragma unroll
      for (int rr = 0; rr < 4; rr++) {
        const int m = wm + i * 16 + fq * 4 + rr;
        hfull[(long)m * 64 * 512 + n] = __float2bfloat16(tanhf(acc[i][j][rr] + bv));
      }
  }
}

// ---------------- gi GEMM: gi = gather(W_embed,cap) @ W_ih^T + b_ih ----------------
// A: bf16 gather via per-lane gload. B: bf16 gload. grid (12, 63).
__global__ __launch_bounds__(256) void GG_gemm_gi(
    const __hip_bfloat16* __restrict__ WembB,  // [V][512] bf16
    const int* __restrict__ cap,               // [B][L] int32
    const __hip_bfloat16* __restrict__ WihB,   // [G][512] bf16
    const float* __restrict__ bias,            // [G] f32
    __hip_bfloat16* __restrict__ C) {          // [M][G]
  __shared__ short sA[128 * 64];
  __shared__ short sB[128 * 64];
  const int lane = threadIdx.x & 63;
  const int wave = threadIdx.x >> 6;
  const int m0 = blockIdx.y * 128;
  const int n0 = blockIdx.x * 128;
  const int srow = lane >> 3;
  const int scol = (lane & 7) * 8;

  f32x4_t acc[4][4] = {};

  const __hip_bfloat16* aptr[4];
  const __hip_bfloat16* bptr[4];
#pragma unroll
  for (int i = 0; i < 4; i++) {
    const int r = (wave * 4 + i) * 8 + srow;
    const int bt = m0 + r;
    const int bb = bt / 63;
    const int tt = bt - bb * 63;
    aptr[i] = WembB + (long)cap[bb * L_ + tt] * 512 + scol;
    bptr[i] = WihB + (long)(n0 + r) * 512 + scol;
  }

  const int wm = (wave >> 1) * 64;
  const int wn = (wave & 1) * 64;
  const int fr = lane & 15;
  const int fk = (lane >> 4) * 8;

  for (int kt = 0; kt < 8; kt++) {
    __syncthreads();
#pragma unroll
    for (int i = 0; i < 4; i++) {
      const int chunk = wave * 4 + i;
      gload_lds16(aptr[i] + kt * 64, sA + chunk * 512);
      gload_lds16(bptr[i] + kt * 64, sB + chunk * 512);
    }
    __syncthreads();
#pragma unroll
    for (int kk = 0; kk < 2; kk++) {
      bf16x8_t a[4], b[4];
#pragma unroll
      for (int i = 0; i < 4; i++) {
        a[i] = lds_frag(sA + (wm + i * 16 + fr) * 64 + kk * 32 + fk);
        b[i] = lds_frag(sB + (wn + i * 16 + fr) * 64 + kk * 32 + fk);
      }
#pragma unroll
      for (int i = 0; i < 4; i++)
#pragma unroll
        for (int j = 0; j < 4; j++)
          acc[i][j] = __builtin_amdgcn_mfma_f32_16x16x32_bf16(a[i], b[j], acc[i][j], 0, 0, 0);
    }
  }

  const int fq = lane >> 4;
#pragma unroll
  for (int j = 0; j < 4; j++) {
    const int n = n0 + wn + j * 16 + fr;
    const float bv = bias[n];
#pragma unroll
    for (int i = 0; i < 4; i++)
#pragma unroll
      for (int rr = 0; rr < 4; rr++) {
        const int m = m0 + wm + i * 16 + fq * 4 + rr;
        C[(long)m * G_ + n] = __float2bfloat16(acc[i][j][rr] + bv);
      }
  }
}

// ---------------- logits GEMM: logits = hs @ W_fc^T + b_fc ----------------
// 1D grid 5040 = 8 xcd * 10 colband * 63 rows; xcd owns fixed col band (L2 reuse).
template <bool BBF16>
__global__ __launch_bounds__(256) void GG_gemm_logits(
    const __hip_bfloat16* __restrict__ hfull,  // [B][64][512]
    const void* __restrict__ Bsrc,             // W_fc bf16 or f32 [V][512]
    const float* __restrict__ bias,            // [V] f32
    float* __restrict__ C) {                   // [M][V]
  const int flat = blockIdx.x;
  const int xcd = flat & 7;
  const int s = flat >> 3;           // 0..629
  const int col = xcd * 10 + s % 10; // 0..79
  const int row = s / 10;            // 0..62
  if (col >= 79) return;
  const int m0 = row * 128;
  const int n0 = col * 128;

  __shared__ short sA[128 * 64];
  __shared__ short sB[128 * 64];
  const int lane = threadIdx.x & 63;
  const int wave = threadIdx.x >> 6;
  const int srow = lane >> 3;
  const int scol = (lane & 7) * 8;

  f32x4_t acc[4][4] = {};

  const __hip_bfloat16* aptr[4];
  const __hip_bfloat16* bptrB[4];
  const float* bptrF[4];
#pragma unroll
  for (int i = 0; i < 4; i++) {
    const int r = (wave * 4 + i) * 8 + srow;
    const int m = m0 + r;
    const int bb = m / 63;
    const int tt = m - bb * 63;
    aptr[i] = hfull + ((long)bb * 64 + tt + 1) * 512 + scol;
    int nrow = n0 + r;
    nrow = (nrow < V_) ? nrow : (V_ - 1);
    if constexpr (BBF16) bptrB[i] = (const __hip_bfloat16*)Bsrc + (long)nrow * 512 + scol;
    else                 bptrF[i] = (const float*)Bsrc + (long)nrow * 512 + scol;
  }

  const int wm = (wave >> 1) * 64;
  const int wn = (wave & 1) * 64;
  const int fr = lane & 15;
  const int fk = (lane >> 4) * 8;

  for (int kt = 0; kt < 8; kt++) {
    s16x8_t vb[4];
    if constexpr (!BBF16) {
#pragma unroll
      for (int i = 0; i < 4; i++) vb[i] = cvt8(bptrF[i] + kt * 64);
    }
    __syncthreads();
#pragma unroll
    for (int i = 0; i < 4; i++) {
      const int chunk = wave * 4 + i;
      gload_lds16(aptr[i] + kt * 64, sA + chunk * 512);
      if constexpr (BBF16)
        gload_lds16(bptrB[i] + kt * 64, sB + chunk * 512);
      else
        *reinterpret_cast<s16x8_t*>(sB + chunk * 512 + lane * 8) = vb[i];
    }
    __syncthreads();
#pragma unroll
    for (int kk = 0; kk < 2; kk++) {
      bf16x8_t a[4], b[4];
#pragma unroll
      for (int i = 0; i < 4; i++) {
        a[i] = lds_frag(sA + (wm + i * 16 + fr) * 64 + kk * 32 + fk);
        b[i] = lds_frag(sB + (wn + i * 16 + fr) * 64 + kk * 32 + fk);
      }
#pragma unroll
      for (int i = 0; i < 4; i++)
#pragma unroll
        for (int j = 0; j < 4; j++)
          acc[i][j] = __builtin_amdgcn_mfma_f32_16x16x32_bf16(a[i], b[j], acc[i][j], 0, 0, 0);
    }
  }

  const int fq = lane >> 4;
#pragma unroll
  for (int j = 0; j < 4; j++) {
    const int n = n0 + wn + j * 16 + fr;
    if (n >= V_) continue;
    const float bv = bias[n];
#pragma unroll
    for (int i = 0; i < 4; i++)
#pragma unroll
      for (int rr = 0; rr < 4; rr++) {
        const int m = m0 + wm + i * 16 + fq * 4 + rr;
        C[(long)m * V_ + n] = acc[i][j][rr] + bv;
      }
  }
}

// ---------------- persistent GRU scan ----------------
// 32 blocks (co-resident, 1/CU); block owns 16-wide d-strip. Whh strip (48x512)
// LDS-resident for all 63 steps (XOR-swizzled). Grid barrier between steps via
// agent-scope atomics (release/acquire handle cross-XCD L2 wb/inv).
__global__ __launch_bounds__(256) void GG_scan_persist(
    __hip_bfloat16* __restrict__ hfull,       // [B][64][512]
    const __hip_bfloat16* __restrict__ gi,    // [M][G]
    const __hip_bfloat16* __restrict__ WhhB,  // [G][512] bf16
    const float* __restrict__ bhh,            // [G] f32
    int* __restrict__ ctr) {
  __shared__ short sW[48 * 512];      // 49,152 B, persistent
  __shared__ short sA[2][128 * 64];   // 32,768 B, h-tile double buffer
  const int lane = threadIdx.x & 63;
  const int wave = threadIdx.x >> 6;
  const int d0 = blockIdx.x * 16;
  const int g4 = lane >> 4;
  const int fr = lane & 15;
  const int sgcol = ((lane & 7) ^ (lane >> 3)) * 8;  // inverse-swizzled source granule

  // Load Whh strip into LDS once. LDS row rr (0..47) = gate (rr>>4), col d0+(rr&15).
  // Source col granule pre-swizzled: lane l -> granule l ^ (rr&7); read side XORs back.
  for (int rr = wave; rr < 48; rr += 4) {
    const int grow = (rr >> 4) * 512 + d0 + (rr & 15);
    gload_lds16(WhhB + (long)grow * 512 + (lane ^ (rr & 7)) * 8, sW + rr * 512);
  }

  const int dd = d0 + fr;
  const float br_ = bhh[dd], bz_ = bhh[512 + dd], bn_ = bhh[1024 + dd];
  const short* gis = (const short*)gi;

  for (int t = 0; t < T_; t++) {
    if (t > 0) {
      if (threadIdx.x == 0) {
        while (__hip_atomic_load(ctr, __ATOMIC_ACQUIRE, __HIP_MEMORY_SCOPE_AGENT) <
               t * SCAN_NB)
          __builtin_amdgcn_s_sleep(1);
      }
      __syncthreads();  // all waves see post-acquire state
    }

    f32x4_t acc[2][3] = {};
    // stage h[t] tile [128][64] for kt into buf; linear LDS dest, swizzled source col
#define STAGE_H(buf, kt)                                                               \
    {                                                                                  \
      _Pragma("unroll")                                                                \
      for (int c = wave; c < 16; c += 4) {                                             \
        const int b = c * 8 + (lane >> 3);                                             \
        gload_lds16(hfull + ((long)b * 64 + t) * 512 + (kt) * 64 + sgcol,              \
                    &sA[buf][c * 512]);                                                \
      }                                                                                \
    }
    STAGE_H(0, 0)
    int cur = 0;
#pragma unroll
    for (int kt = 0; kt < 8; kt++) {
      __syncthreads();               // buf[cur] staged (vmcnt drained at barrier)
      if (kt < 7) STAGE_H(cur ^ 1, kt + 1)
#pragma unroll
      for (int kk = 0; kk < 2; kk++) {
        bf16x8_t bfr[3], afr[2];
#pragma unroll
        for (int j = 0; j < 3; j++) {
          const int gg = (kt * 8 + kk * 4 + g4) ^ (fr & 7);
          bfr[j] = lds_frag(sW + (j * 16 + fr) * 512 + gg * 8);
        }
#pragma unroll
        for (int i = 0; i < 2; i++) {
          const int gg = (kk * 4 + g4) ^ (fr & 7);
          afr[i] = lds_frag(&sA[cur][(wave * 32 + i * 16 + fr) * 64 + gg * 8]);
        }
#pragma unroll
        for (int i = 0; i < 2; i++)
#pragma unroll
          for (int j = 0; j < 3; j++)
            acc[i][j] = __builtin_amdgcn_mfma_f32_16x16x32_bf16(afr[i], bfr[j], acc[i][j], 0, 0, 0);
      }
      cur ^= 1;
    }

    // epilogue: fused gates, write h[t+1]
#pragma unroll
    for (int i = 0; i < 2; i++)
#pragma unroll
      for (int rr = 0; rr < 4; rr++) {
        const int b = wave * 32 + i * 16 + g4 * 4 + rr;
        const long gbase = ((long)b * T_ + t) * (long)G_;
        const float ir  = bf2f(gis[gbase + dd]);
        const float iz  = bf2f(gis[gbase + 512 + dd]);
        const float in_ = bf2f(gis[gbase + 1024 + dd]);
        const float rg = sigmoidf_(ir + acc[i][0][rr] + br_);
        const float zg = sigmoidf_(iz + acc[i][1][rr] + bz_);
        const float ng = tanhf(in_ + rg * (acc[i][2][rr] + bn_));
        const float hp = bf2f(*(const short*)&hfull[((long)b * 64 + t) * 512 + dd]);
        hfull[((long)b * 64 + t + 1) * 512 + dd] = __float2bfloat16((1.f - zg) * ng + zg * hp);
      }

    if (t < T_ - 1) {
      __syncthreads();  // all waves' h stores drained (barrier waits vmcnt 0)
      if (threadIdx.x == 0)
        __hip_atomic_fetch_add(ctr, 1, __ATOMIC_RELEASE, __HIP_MEMORY_SCOPE_AGENT);
    }
#undef STAGE_H
  }
}

// ---------------- tail: out[LOGITS_SZ + b] = f32(len[b] - 1) ----------------
__global__ void GG_tail_kernel(const int* __restrict__ lens, float* __restrict__ out) {
  const int b = threadIdx.x;
  if (b < B_) out[LOGITS_SZ + b] = (float)(lens[b] - 1);
}

extern "C" void kernel_launch(void* const* d_in, const int* in_sizes, int n_in,
                              void* d_out, int out_size, void* d_ws, size_t ws_size,
                              hipStream_t stream) {
  const float* gf      = (const float*)d_in[0];
  const int*   cap     = (const int*)d_in[1];
  const int*   lens    = (const int*)d_in[2];
  const float* W_embed = (const float*)d_in[3];
  const float* W_init  = (const float*)d_in[4];
  const float* b_init  = (const float*)d_in[5];
  const float* W_ih    = (const float*)d_in[6];
  const float* W_hh    = (const float*)d_in[7];
  const float* b_ih    = (const float*)d_in[8];
  const float* b_hh    = (const float*)d_in[9];
  const float* W_fc    = (const float*)d_in[10];
  const float* b_fc    = (const float*)d_in[11];
  float* out = (float*)d_out;

  // d_out scratch (all consumed before the logits GEMM writes d_out):
  char* ob = (char*)d_out;
  __hip_bfloat16* gi_ws  = (__hip_bfloat16*)ob;               // [0, 24,772,608)
  __hip_bfloat16* WhhB   = (__hip_bfloat16*)(ob + 25165824);  // 1.5 MB
  __hip_bfloat16* WihB   = (__hip_bfloat16*)(ob + 27262976);  // 1.5 MB
  __hip_bfloat16* WembB  = (__hip_bfloat16*)(ob + 29360128);  // 10 MB
  __hip_bfloat16* WinitB = (__hip_bfloat16*)(ob + 40894464);  // 2 MB
  __hip_bfloat16* gfB    = (__hip_bfloat16*)(ob + 43253760);  // 0.5 MB

  // ws: hfull [B][64][512] bf16 (slot 0 = h0, slot t+1 = h_t), + WfcB + ctr
  __hip_bfloat16* hfull = (__hip_bfloat16*)d_ws;
  __hip_bfloat16* WfcB  = (__hip_bfloat16*)((char*)d_ws + 8388608);
  const bool big_ws = ws_size >= (size_t)(8388608 + 10240000 + 256);
  int* ctr = (int*)((char*)d_ws + (big_ws ? 18628608 : 8388608));

  // 0. reset grid-barrier counter (graph-replayed every call -> deterministic)
  hipMemsetAsync(ctr, 0, 256, stream);

  // 1. weight/input converts to bf16
  GG_cvt_kernel<<<dim3((G_ * D_ / 8 + 255) / 256), 256, 0, stream>>>(W_hh, WhhB, G_ * D_ / 8);
  GG_cvt_kernel<<<dim3((G_ * D_ / 8 + 255) / 256), 256, 0, stream>>>(W_ih, WihB, G_ * D_ / 8);
  GG_cvt_kernel<<<dim3((V_ * D_ / 8 + 255) / 256), 256, 0, stream>>>(W_embed, WembB, V_ * D_ / 8);
  GG_cvt_kernel<<<dim3((D_ * ENC_ / 8 + 255) / 256), 256, 0, stream>>>(W_init, WinitB, D_ * ENC_ / 8);
  GG_cvt_kernel<<<dim3((B_ * ENC_ / 8 + 255) / 256), 256, 0, stream>>>(gf, gfB, B_ * ENC_ / 8);
  if (big_ws)
    GG_cvt_kernel<<<dim3((V_ * D_ / 8 + 255) / 256), 256, 0, stream>>>(W_fc, WfcB, V_ * D_ / 8);

  // 2. h0 -> hfull slot 0 (MFMA GEMM, 4 blocks)
  GG_gemm_h0<<<dim3(4), 256, 0, stream>>>(gfB, WinitB, b_init, hfull);

  // 3. gi = gather(W_embed, cap) @ W_ih^T + b_ih
  GG_gemm_gi<<<dim3(G_ / 128, M_ / 128), 256, 0, stream>>>(WembB, cap, WihB, b_ih, gi_ws);

  // 4. GRU scan: single persistent kernel, 63 steps with internal grid barrier
  GG_scan_persist<<<dim3(SCAN_NB), 256, 0, stream>>>(hfull, gi_ws, WhhB, b_hh, ctr);

  // 5. logits (XCD-banded swizzle, 5040 = 8*10*63 padded blocks)
  if (big_ws)
    GG_gemm_logits<true><<<dim3(5040), 256, 0, stream>>>(hfull, WfcB, b_fc, out);
  else
    GG_gemm_logits<false><<<dim3(5040), 256, 0, stream>>>(hfull, W_fc, b_fc, out);

  // 6. second output
  GG_tail_kernel<<<dim3(1), 128, 0, stream>>>(lens, out);
}

// Round 6
// 613.639 us; speedup vs baseline: 5.3237x; 1.4840x over previous
//
#include <hip/hip_runtime.h>
#include <hip/hip_bf16.h>

// Problem dims
#define V_    10000
#define ENC_  2048
#define D_    512
#define B_    128
#define L_    64
#define T_    63          // L-1 timesteps
#define M_    (B_ * L_ - B_)   // 8064 rows (b*63 + t)
#define G_    (3 * D_)    // 1536 gate width
#define LOGITS_SZ ((long)M_ * V_)   // 80,640,000
#define SCAN_NB 64        // 2 batch-halves x 32 d-strips

typedef __bf16 bf16x8_t __attribute__((ext_vector_type(8)));
typedef float  f32x4_t  __attribute__((ext_vector_type(4)));
typedef short  s16x8_t  __attribute__((ext_vector_type(8)));

typedef __attribute__((address_space(3))) char*       lds_cptr_t;
typedef const __attribute__((address_space(1))) char* glb_cptr_t;

// wave-uniform LDS dest; HW writes lane l at dest + l*16B. Global src is per-lane.
__device__ __forceinline__ void gload_lds16(const void* g, void* l) {
  __builtin_amdgcn_global_load_lds((glb_cptr_t)g, (lds_cptr_t)l, 16, 0, 0);
}
__device__ __forceinline__ float bf2f(short s) {
  return __uint_as_float(((unsigned)(unsigned short)s) << 16);
}
__device__ __forceinline__ short f2bf(float f) {
  __hip_bfloat16 h = __float2bfloat16(f);  // RNE
  return *reinterpret_cast<short*>(&h);
}
__device__ __forceinline__ s16x8_t cvt8(const float* p) {
  f32x4_t lo = *reinterpret_cast<const f32x4_t*>(p);
  f32x4_t hi = *reinterpret_cast<const f32x4_t*>(p + 4);
  s16x8_t r;
#pragma unroll
  for (int e = 0; e < 4; e++) { r[e] = f2bf(lo[e]); r[4 + e] = f2bf(hi[e]); }
  return r;
}
__device__ __forceinline__ float sigmoidf_(float x) {
  return 1.0f / (1.0f + __expf(-x));
}
__device__ __forceinline__ bf16x8_t lds_frag(const short* p) {
  return __builtin_bit_cast(bf16x8_t, *reinterpret_cast<const s16x8_t*>(p));
}

// ---------------- f32 -> bf16 bulk convert ----------------
__global__ void GG_cvt_kernel(const float* __restrict__ src,
                              __hip_bfloat16* __restrict__ dst, int n8) {
  int i = blockIdx.x * blockDim.x + threadIdx.x;
  if (i < n8) {
    s16x8_t v = cvt8(src + (long)i * 8);
    *reinterpret_cast<s16x8_t*>(dst + (long)i * 8) = v;
  }
}

// ---------------- h0 GEMM: hfull[b][0][:] = tanh(gf @ W_init^T + b_init) ----------------
__global__ __launch_bounds__(256) void GG_gemm_h0(
    const __hip_bfloat16* __restrict__ gfB,     // [128][2048] bf16
    const __hip_bfloat16* __restrict__ WinitB,  // [512][2048] bf16
    const float* __restrict__ binit,            // [512] f32
    __hip_bfloat16* __restrict__ hfull) {       // [B][64][512]
  __shared__ short sA[128 * 64];
  __shared__ short sB[128 * 64];
  const int lane = threadIdx.x & 63;
  const int wave = threadIdx.x >> 6;
  const int n0 = blockIdx.x * 128;
  const int srow = lane >> 3;
  const int scol = (lane & 7) * 8;

  f32x4_t acc[4][4] = {};

  const __hip_bfloat16* aptr[4];
  const __hip_bfloat16* bptr[4];
#pragma unroll
  for (int i = 0; i < 4; i++) {
    const int r = (wave * 4 + i) * 8 + srow;
    aptr[i] = gfB + (long)r * ENC_ + scol;
    bptr[i] = WinitB + (long)(n0 + r) * ENC_ + scol;
  }

  const int wm = (wave >> 1) * 64;
  const int wn = (wave & 1) * 64;
  const int fr = lane & 15;
  const int fk = (lane >> 4) * 8;

  for (int kt = 0; kt < 32; kt++) {
    __syncthreads();
#pragma unroll
    for (int i = 0; i < 4; i++) {
      const int chunk = wave * 4 + i;
      gload_lds16(aptr[i] + kt * 64, sA + chunk * 512);
      gload_lds16(bptr[i] + kt * 64, sB + chunk * 512);
    }
    __syncthreads();
#pragma unroll
    for (int kk = 0; kk < 2; kk++) {
      bf16x8_t a[4], b[4];
#pragma unroll
      for (int i = 0; i < 4; i++) {
        a[i] = lds_frag(sA + (wm + i * 16 + fr) * 64 + kk * 32 + fk);
        b[i] = lds_frag(sB + (wn + i * 16 + fr) * 64 + kk * 32 + fk);
      }
#pragma unroll
      for (int i = 0; i < 4; i++)
#pragma unroll
        for (int j = 0; j < 4; j++)
          acc[i][j] = __builtin_amdgcn_mfma_f32_16x16x32_bf16(a[i], b[j], acc[i][j], 0, 0, 0);
    }
  }

  const int fq = lane >> 4;
#pragma unroll
  for (int j = 0; j < 4; j++) {
    const int n = n0 + wn + j * 16 + fr;
    const float bv = binit[n];
#pragma unroll
    for (int i = 0; i < 4; i++)
#pragma unroll
      for (int rr = 0; rr < 4; rr++) {
        const int m = wm + i * 16 + fq * 4 + rr;
        hfull[(long)m * 64 * 512 + n] = __float2bfloat16(tanhf(acc[i][j][rr] + bv));
      }
  }
}

// ---------------- gi GEMM: gi = gather(W_embed,cap) @ W_ih^T + b_ih ----------------
__global__ __launch_bounds__(256) void GG_gemm_gi(
    const __hip_bfloat16* __restrict__ WembB,  // [V][512] bf16
    const int* __restrict__ cap,               // [B][L] int32
    const __hip_bfloat16* __restrict__ WihB,   // [G][512] bf16
    const float* __restrict__ bias,            // [G] f32
    __hip_bfloat16* __restrict__ C) {          // [M][G]
  __shared__ short sA[128 * 64];
  __shared__ short sB[128 * 64];
  const int lane = threadIdx.x & 63;
  const int wave = threadIdx.x >> 6;
  const int m0 = blockIdx.y * 128;
  const int n0 = blockIdx.x * 128;
  const int srow = lane >> 3;
  const int scol = (lane & 7) * 8;

  f32x4_t acc[4][4] = {};

  const __hip_bfloat16* aptr[4];
  const __hip_bfloat16* bptr[4];
#pragma unroll
  for (int i = 0; i < 4; i++) {
    const int r = (wave * 4 + i) * 8 + srow;
    const int bt = m0 + r;
    const int bb = bt / 63;
    const int tt = bt - bb * 63;
    aptr[i] = WembB + (long)cap[bb * L_ + tt] * 512 + scol;
    bptr[i] = WihB + (long)(n0 + r) * 512 + scol;
  }

  const int wm = (wave >> 1) * 64;
  const int wn = (wave & 1) * 64;
  const int fr = lane & 15;
  const int fk = (lane >> 4) * 8;

  for (int kt = 0; kt < 8; kt++) {
    __syncthreads();
#pragma unroll
    for (int i = 0; i < 4; i++) {
      const int chunk = wave * 4 + i;
      gload_lds16(aptr[i] + kt * 64, sA + chunk * 512);
      gload_lds16(bptr[i] + kt * 64, sB + chunk * 512);
    }
    __syncthreads();
#pragma unroll
    for (int kk = 0; kk < 2; kk++) {
      bf16x8_t a[4], b[4];
#pragma unroll
      for (int i = 0; i < 4; i++) {
        a[i] = lds_frag(sA + (wm + i * 16 + fr) * 64 + kk * 32 + fk);
        b[i] = lds_frag(sB + (wn + i * 16 + fr) * 64 + kk * 32 + fk);
      }
#pragma unroll
      for (int i = 0; i < 4; i++)
#pragma unroll
        for (int j = 0; j < 4; j++)
          acc[i][j] = __builtin_amdgcn_mfma_f32_16x16x32_bf16(a[i], b[j], acc[i][j], 0, 0, 0);
    }
  }

  const int fq = lane >> 4;
#pragma unroll
  for (int j = 0; j < 4; j++) {
    const int n = n0 + wn + j * 16 + fr;
    const float bv = bias[n];
#pragma unroll
    for (int i = 0; i < 4; i++)
#pragma unroll
      for (int rr = 0; rr < 4; rr++) {
        const int m = m0 + wm + i * 16 + fq * 4 + rr;
        C[(long)m * G_ + n] = __float2bfloat16(acc[i][j][rr] + bv);
      }
  }
}

// ---------------- logits GEMM: logits = hs @ W_fc^T + b_fc ----------------
template <bool BBF16>
__global__ __launch_bounds__(256) void GG_gemm_logits(
    const __hip_bfloat16* __restrict__ hfull,  // [B][64][512]
    const void* __restrict__ Bsrc,             // W_fc bf16 or f32 [V][512]
    const float* __restrict__ bias,            // [V] f32
    float* __restrict__ C) {                   // [M][V]
  const int flat = blockIdx.x;
  const int xcd = flat & 7;
  const int s = flat >> 3;           // 0..629
  const int col = xcd * 10 + s % 10; // 0..79
  const int row = s / 10;            // 0..62
  if (col >= 79) return;
  const int m0 = row * 128;
  const int n0 = col * 128;

  __shared__ short sA[128 * 64];
  __shared__ short sB[128 * 64];
  const int lane = threadIdx.x & 63;
  const int wave = threadIdx.x >> 6;
  const int srow = lane >> 3;
  const int scol = (lane & 7) * 8;

  f32x4_t acc[4][4] = {};

  const __hip_bfloat16* aptr[4];
  const __hip_bfloat16* bptrB[4];
  const float* bptrF[4];
#pragma unroll
  for (int i = 0; i < 4; i++) {
    const int r = (wave * 4 + i) * 8 + srow;
    const int m = m0 + r;
    const int bb = m / 63;
    const int tt = m - bb * 63;
    aptr[i] = hfull + ((long)bb * 64 + tt + 1) * 512 + scol;
    int nrow = n0 + r;
    nrow = (nrow < V_) ? nrow : (V_ - 1);
    if constexpr (BBF16) bptrB[i] = (const __hip_bfloat16*)Bsrc + (long)nrow * 512 + scol;
    else                 bptrF[i] = (const float*)Bsrc + (long)nrow * 512 + scol;
  }

  const int wm = (wave >> 1) * 64;
  const int wn = (wave & 1) * 64;
  const int fr = lane & 15;
  const int fk = (lane >> 4) * 8;

  for (int kt = 0; kt < 8; kt++) {
    s16x8_t vb[4];
    if constexpr (!BBF16) {
#pragma unroll
      for (int i = 0; i < 4; i++) vb[i] = cvt8(bptrF[i] + kt * 64);
    }
    __syncthreads();
#pragma unroll
    for (int i = 0; i < 4; i++) {
      const int chunk = wave * 4 + i;
      gload_lds16(aptr[i] + kt * 64, sA + chunk * 512);
      if constexpr (BBF16)
        gload_lds16(bptrB[i] + kt * 64, sB + chunk * 512);
      else
        *reinterpret_cast<s16x8_t*>(sB + chunk * 512 + lane * 8) = vb[i];
    }
    __syncthreads();
#pragma unroll
    for (int kk = 0; kk < 2; kk++) {
      bf16x8_t a[4], b[4];
#pragma unroll
      for (int i = 0; i < 4; i++) {
        a[i] = lds_frag(sA + (wm + i * 16 + fr) * 64 + kk * 32 + fk);
        b[i] = lds_frag(sB + (wn + i * 16 + fr) * 64 + kk * 32 + fk);
      }
#pragma unroll
      for (int i = 0; i < 4; i++)
#pragma unroll
        for (int j = 0; j < 4; j++)
          acc[i][j] = __builtin_amdgcn_mfma_f32_16x16x32_bf16(a[i], b[j], acc[i][j], 0, 0, 0);
    }
  }

  const int fq = lane >> 4;
#pragma unroll
  for (int j = 0; j < 4; j++) {
    const int n = n0 + wn + j * 16 + fr;
    if (n >= V_) continue;
    const float bv = bias[n];
#pragma unroll
    for (int i = 0; i < 4; i++)
#pragma unroll
      for (int rr = 0; rr < 4; rr++) {
        const int m = m0 + wm + i * 16 + fq * 4 + rr;
        C[(long)m * V_ + n] = acc[i][j][rr] + bv;
      }
  }
}

// ---------------- persistent GRU scan, v2 ----------------
// 64 blocks = 2 batch-halves x 32 d-strips. Block: M=64 (its half's rows),
// N=48 (3 gates x 16 d), K=512. Wave w owns batch rows [w*16, w*16+16):
// stages ONLY those rows -> no intra-step barriers, single vmcnt(0) wait.
// Whh strip (48x512) LDS-resident all 63 steps. Two independent grid-barrier
// groups of 32 (halves share no data). gi prefetched before the spin;
// h_prev register-carried.
__global__ __launch_bounds__(256) void GG_scan_persist(
    __hip_bfloat16* __restrict__ hfull,       // [B][64][512]
    const __hip_bfloat16* __restrict__ gi,    // [M][G]
    const __hip_bfloat16* __restrict__ WhhB,  // [G][512] bf16
    const float* __restrict__ bhh,            // [G] f32
    int* __restrict__ ctr) {
  __shared__ short sW[48 * 512];      // 49,152 B, persistent
  __shared__ short sA[4][16 * 512];   // 65,536 B, per-wave h rows
  const int lane = threadIdx.x & 63;
  const int wave = threadIdx.x >> 6;
  const int strip = blockIdx.x & 31;
  const int half  = blockIdx.x >> 5;
  const int d0 = strip * 16;
  const int fr = lane & 15;
  const int g4 = lane >> 4;            // 0..3
  int* myctr = ctr + half * 32;        // 128B apart

  // one-time: stage Whh strip, XOR-swizzled source granules
  for (int rr = wave; rr < 48; rr += 4) {
    const int grow = (rr >> 4) * 512 + d0 + (rr & 15);
    gload_lds16(WhhB + (long)grow * 512 + (lane ^ (rr & 7)) * 8, sW + rr * 512);
  }

  const int dd = d0 + fr;
  const int bbase = half * 64 + wave * 16 + g4 * 4;  // thread's 4 batch rows
  const float br_ = bhh[dd], bz_ = bhh[512 + dd], bn_ = bhh[1024 + dd];
  const short* gis = (const short*)gi;
  short* sAw = &sA[wave][0];

  // hp registers from h0 (written by prior dispatch)
  float hp[4];
#pragma unroll
  for (int rr = 0; rr < 4; rr++)
    hp[rr] = bf2f(*(const short*)&hfull[((long)(bbase + rr) * 64) * 512 + dd]);

  asm volatile("s_waitcnt vmcnt(0)" ::: "memory");
  __syncthreads();  // sW fully staged (all waves)

  for (int t = 0; t < T_; t++) {
    // gi prefetch (independent of h[t]; hides under barrier spin)
    short gir[4], giz[4], gin[4];
#pragma unroll
    for (int rr = 0; rr < 4; rr++) {
      const long gbase = ((long)(bbase + rr) * T_ + t) * (long)G_;
      gir[rr] = gis[gbase + dd];
      giz[rr] = gis[gbase + 512 + dd];
      gin[rr] = gis[gbase + 1024 + dd];
    }

    if (t > 0) {
      if (threadIdx.x == 0) {
        while (__hip_atomic_load(myctr, __ATOMIC_ACQUIRE, __HIP_MEMORY_SCOPE_AGENT) <
               t * 32)
          __builtin_amdgcn_s_sleep(1);
      }
      __syncthreads();
    }

    // stage own 16 rows of h[t], full K=512; swizzled source granules
#pragma unroll
    for (int r = 0; r < 16; r++) {
      const int b = half * 64 + wave * 16 + r;
      gload_lds16(hfull + ((long)b * 64 + t) * 512 + (lane ^ (r & 7)) * 8,
                  sAw + r * 512);
    }
    asm volatile("s_waitcnt vmcnt(0)" ::: "memory");
    __builtin_amdgcn_sched_barrier(0);

    f32x4_t acc[3] = {};
#pragma unroll
    for (int kt = 0; kt < 8; kt++)
#pragma unroll
      for (int kk = 0; kk < 2; kk++) {
        const int kg = kt * 8 + kk * 4 + g4;
        const int gsw = (kg ^ (fr & 7)) * 8;
        bf16x8_t afr = lds_frag(sAw + fr * 512 + gsw);
        bf16x8_t bfr[3];
#pragma unroll
        for (int j = 0; j < 3; j++) bfr[j] = lds_frag(sW + (j * 16 + fr) * 512 + gsw);
#pragma unroll
        for (int j = 0; j < 3; j++)
          acc[j] = __builtin_amdgcn_mfma_f32_16x16x32_bf16(afr, bfr[j], acc[j], 0, 0, 0);
      }

    // fused gates; h[t+1] store; hp carried in regs (rounded to stored bf16)
#pragma unroll
    for (int rr = 0; rr < 4; rr++) {
      const float rg = sigmoidf_(bf2f(gir[rr]) + acc[0][rr] + br_);
      const float zg = sigmoidf_(bf2f(giz[rr]) + acc[1][rr] + bz_);
      const float ng = tanhf(bf2f(gin[rr]) + rg * (acc[2][rr] + bn_));
      const short hnb = f2bf((1.f - zg) * ng + zg * hp[rr]);
      hp[rr] = bf2f(hnb);
      *(short*)&hfull[((long)(bbase + rr) * 64 + t + 1) * 512 + dd] = hnb;
    }

    if (t < T_ - 1) {
      __syncthreads();  // all waves' h stores drained before release
      if (threadIdx.x == 0)
        __hip_atomic_fetch_add(myctr, 1, __ATOMIC_RELEASE, __HIP_MEMORY_SCOPE_AGENT);
    }
  }
}

// ---------------- tail: out[LOGITS_SZ + b] = f32(len[b] - 1) ----------------
__global__ void GG_tail_kernel(const int* __restrict__ lens, float* __restrict__ out) {
  const int b = threadIdx.x;
  if (b < B_) out[LOGITS_SZ + b] = (float)(lens[b] - 1);
}

extern "C" void kernel_launch(void* const* d_in, const int* in_sizes, int n_in,
                              void* d_out, int out_size, void* d_ws, size_t ws_size,
                              hipStream_t stream) {
  const float* gf      = (const float*)d_in[0];
  const int*   cap     = (const int*)d_in[1];
  const int*   lens    = (const int*)d_in[2];
  const float* W_embed = (const float*)d_in[3];
  const float* W_init  = (const float*)d_in[4];
  const float* b_init  = (const float*)d_in[5];
  const float* W_ih    = (const float*)d_in[6];
  const float* W_hh    = (const float*)d_in[7];
  const float* b_ih    = (const float*)d_in[8];
  const float* b_hh    = (const float*)d_in[9];
  const float* W_fc    = (const float*)d_in[10];
  const float* b_fc    = (const float*)d_in[11];
  float* out = (float*)d_out;

  // d_out scratch (all consumed before the logits GEMM writes d_out):
  char* ob = (char*)d_out;
  __hip_bfloat16* gi_ws  = (__hip_bfloat16*)ob;               // [0, 24,772,608)
  __hip_bfloat16* WhhB   = (__hip_bfloat16*)(ob + 25165824);  // 1.5 MB
  __hip_bfloat16* WihB   = (__hip_bfloat16*)(ob + 27262976);  // 1.5 MB
  __hip_bfloat16* WembB  = (__hip_bfloat16*)(ob + 29360128);  // 10 MB
  __hip_bfloat16* WinitB = (__hip_bfloat16*)(ob + 40894464);  // 2 MB
  __hip_bfloat16* gfB    = (__hip_bfloat16*)(ob + 43253760);  // 0.5 MB

  // ws: hfull [B][64][512] bf16 (slot 0 = h0, slot t+1 = h_t), + WfcB + ctr
  __hip_bfloat16* hfull = (__hip_bfloat16*)d_ws;
  __hip_bfloat16* WfcB  = (__hip_bfloat16*)((char*)d_ws + 8388608);
  const bool big_ws = ws_size >= (size_t)(8388608 + 10240000 + 256);
  int* ctr = (int*)((char*)d_ws + (big_ws ? 18628608 : 8388608));

  // 0. reset grid-barrier counters (graph-replayed every call -> deterministic)
  hipMemsetAsync(ctr, 0, 256, stream);

  // 1. weight/input converts to bf16
  GG_cvt_kernel<<<dim3((G_ * D_ / 8 + 255) / 256), 256, 0, stream>>>(W_hh, WhhB, G_ * D_ / 8);
  GG_cvt_kernel<<<dim3((G_ * D_ / 8 + 255) / 256), 256, 0, stream>>>(W_ih, WihB, G_ * D_ / 8);
  GG_cvt_kernel<<<dim3((V_ * D_ / 8 + 255) / 256), 256, 0, stream>>>(W_embed, WembB, V_ * D_ / 8);
  GG_cvt_kernel<<<dim3((D_ * ENC_ / 8 + 255) / 256), 256, 0, stream>>>(W_init, WinitB, D_ * ENC_ / 8);
  GG_cvt_kernel<<<dim3((B_ * ENC_ / 8 + 255) / 256), 256, 0, stream>>>(gf, gfB, B_ * ENC_ / 8);
  if (big_ws)
    GG_cvt_kernel<<<dim3((V_ * D_ / 8 + 255) / 256), 256, 0, stream>>>(W_fc, WfcB, V_ * D_ / 8);

  // 2. h0 -> hfull slot 0 (MFMA GEMM, 4 blocks)
  GG_gemm_h0<<<dim3(4), 256, 0, stream>>>(gfB, WinitB, b_init, hfull);

  // 3. gi = gather(W_embed, cap) @ W_ih^T + b_ih
  GG_gemm_gi<<<dim3(G_ / 128, M_ / 128), 256, 0, stream>>>(WembB, cap, WihB, b_ih, gi_ws);

  // 4. GRU scan: single persistent kernel, 63 steps, 2 barrier groups of 32
  GG_scan_persist<<<dim3(SCAN_NB), 256, 0, stream>>>(hfull, gi_ws, WhhB, b_hh, ctr);

  // 5. logits (XCD-banded swizzle, 5040 = 8*10*63 padded blocks)
  if (big_ws)
    GG_gemm_logits<true><<<dim3(5040), 256, 0, stream>>>(hfull, WfcB, b_fc, out);
  else
    GG_gemm_logits<false><<<dim3(5040), 256, 0, stream>>>(hfull, W_fc, b_fc, out);

  // 6. second output
  GG_tail_kernel<<<dim3(1), 128, 0, stream>>>(lens, out);
}

// Round 7
// 590.034 us; speedup vs baseline: 5.5367x; 1.0400x over previous
//
#include <hip/hip_runtime.h>
#include <hip/hip_bf16.h>

// Problem dims
#define V_    10000
#define ENC_  2048
#define D_    512
#define B_    128
#define L_    64
#define T_    63          // L-1 timesteps
#define M_    (B_ * L_ - B_)   // 8064 rows (b*63 + t)
#define G_    (3 * D_)    // 1536 gate width
#define LOGITS_SZ ((long)M_ * V_)   // 80,640,000
#define SCAN_NB 64        // 2 batch-halves x 32 d-strips

typedef __bf16 bf16x8_t __attribute__((ext_vector_type(8)));
typedef float  f32x4_t  __attribute__((ext_vector_type(4)));
typedef short  s16x8_t  __attribute__((ext_vector_type(8)));

typedef __attribute__((address_space(3))) char*       lds_cptr_t;
typedef const __attribute__((address_space(1))) char* glb_cptr_t;

// wave-uniform LDS dest; HW writes lane l at dest + l*16B. Global src is per-lane.
__device__ __forceinline__ void gload_lds16(const void* g, void* l) {
  __builtin_amdgcn_global_load_lds((glb_cptr_t)g, (lds_cptr_t)l, 16, 0, 0);
}
__device__ __forceinline__ float bf2f(short s) {
  return __uint_as_float(((unsigned)(unsigned short)s) << 16);
}
__device__ __forceinline__ short f2bf(float f) {
  __hip_bfloat16 h = __float2bfloat16(f);  // RNE
  return *reinterpret_cast<short*>(&h);
}
__device__ __forceinline__ s16x8_t cvt8(const float* p) {
  f32x4_t lo = *reinterpret_cast<const f32x4_t*>(p);
  f32x4_t hi = *reinterpret_cast<const f32x4_t*>(p + 4);
  s16x8_t r;
#pragma unroll
  for (int e = 0; e < 4; e++) { r[e] = f2bf(lo[e]); r[4 + e] = f2bf(hi[e]); }
  return r;
}
__device__ __forceinline__ float sigmoidf_(float x) {
  return 1.0f / (1.0f + __expf(-x));
}
__device__ __forceinline__ bf16x8_t lds_frag(const short* p) {
  return __builtin_bit_cast(bf16x8_t, *reinterpret_cast<const s16x8_t*>(p));
}

// ---------------- fused f32 -> bf16 converts (5 segments, 1 launch) ----------------
// n8 ranges: Whh [0,98304) Wih [98304,196608) Wemb [196608,836608)
//            Winit [836608,967680) gf [967680,1000448)
__global__ void GG_cvt5(const float* __restrict__ whh, __hip_bfloat16* __restrict__ dwhh,
                        const float* __restrict__ wih, __hip_bfloat16* __restrict__ dwih,
                        const float* __restrict__ wemb, __hip_bfloat16* __restrict__ dwemb,
                        const float* __restrict__ winit, __hip_bfloat16* __restrict__ dwinit,
                        const float* __restrict__ gf, __hip_bfloat16* __restrict__ dgf) {
  const int i = blockIdx.x * blockDim.x + threadIdx.x;
  const float* s; __hip_bfloat16* d; int off;
  if (i < 98304)        { s = whh;   d = dwhh;   off = i; }
  else if (i < 196608)  { s = wih;   d = dwih;   off = i - 98304; }
  else if (i < 836608)  { s = wemb;  d = dwemb;  off = i - 196608; }
  else if (i < 967680)  { s = winit; d = dwinit; off = i - 836608; }
  else                  { s = gf;    d = dgf;    off = i - 967680; }
  s16x8_t v = cvt8(s + (long)off * 8);
  *reinterpret_cast<s16x8_t*>(d + (long)off * 8) = v;
}

__global__ void GG_cvt_kernel(const float* __restrict__ src,
                              __hip_bfloat16* __restrict__ dst, int n8) {
  int i = blockIdx.x * blockDim.x + threadIdx.x;
  if (i < n8) {
    s16x8_t v = cvt8(src + (long)i * 8);
    *reinterpret_cast<s16x8_t*>(dst + (long)i * 8) = v;
  }
}

// ---------------- h0 GEMM: hfull[b][0][:] = tanh(gf @ W_init^T + b_init) ----------------
__global__ __launch_bounds__(256) void GG_gemm_h0(
    const __hip_bfloat16* __restrict__ gfB,     // [128][2048] bf16
    const __hip_bfloat16* __restrict__ WinitB,  // [512][2048] bf16
    const float* __restrict__ binit,            // [512] f32
    __hip_bfloat16* __restrict__ hfull) {       // [B][64][512]
  __shared__ short sA[128 * 64];
  __shared__ short sB[128 * 64];
  const int lane = threadIdx.x & 63;
  const int wave = threadIdx.x >> 6;
  const int n0 = blockIdx.x * 128;
  const int srow = lane >> 3;
  const int scol = (lane & 7) * 8;

  f32x4_t acc[4][4] = {};

  const __hip_bfloat16* aptr[4];
  const __hip_bfloat16* bptr[4];
#pragma unroll
  for (int i = 0; i < 4; i++) {
    const int r = (wave * 4 + i) * 8 + srow;
    aptr[i] = gfB + (long)r * ENC_ + scol;
    bptr[i] = WinitB + (long)(n0 + r) * ENC_ + scol;
  }

  const int wm = (wave >> 1) * 64;
  const int wn = (wave & 1) * 64;
  const int fr = lane & 15;
  const int fk = (lane >> 4) * 8;

  for (int kt = 0; kt < 32; kt++) {
    __syncthreads();
#pragma unroll
    for (int i = 0; i < 4; i++) {
      const int chunk = wave * 4 + i;
      gload_lds16(aptr[i] + kt * 64, sA + chunk * 512);
      gload_lds16(bptr[i] + kt * 64, sB + chunk * 512);
    }
    __syncthreads();
#pragma unroll
    for (int kk = 0; kk < 2; kk++) {
      bf16x8_t a[4], b[4];
#pragma unroll
      for (int i = 0; i < 4; i++) {
        a[i] = lds_frag(sA + (wm + i * 16 + fr) * 64 + kk * 32 + fk);
        b[i] = lds_frag(sB + (wn + i * 16 + fr) * 64 + kk * 32 + fk);
      }
#pragma unroll
      for (int i = 0; i < 4; i++)
#pragma unroll
        for (int j = 0; j < 4; j++)
          acc[i][j] = __builtin_amdgcn_mfma_f32_16x16x32_bf16(a[i], b[j], acc[i][j], 0, 0, 0);
    }
  }

  const int fq = lane >> 4;
#pragma unroll
  for (int j = 0; j < 4; j++) {
    const int n = n0 + wn + j * 16 + fr;
    const float bv = binit[n];
#pragma unroll
    for (int i = 0; i < 4; i++)
#pragma unroll
      for (int rr = 0; rr < 4; rr++) {
        const int m = wm + i * 16 + fq * 4 + rr;
        hfull[(long)m * 64 * 512 + n] = __float2bfloat16(tanhf(acc[i][j][rr] + bv));
      }
  }
}

// ---------------- gi GEMM: gi = gather(W_embed,cap) @ W_ih^T + b_ih ----------------
__global__ __launch_bounds__(256) void GG_gemm_gi(
    const __hip_bfloat16* __restrict__ WembB,  // [V][512] bf16
    const int* __restrict__ cap,               // [B][L] int32
    const __hip_bfloat16* __restrict__ WihB,   // [G][512] bf16
    const float* __restrict__ bias,            // [G] f32
    __hip_bfloat16* __restrict__ C) {          // [M][G]
  __shared__ short sA[128 * 64];
  __shared__ short sB[128 * 64];
  const int lane = threadIdx.x & 63;
  const int wave = threadIdx.x >> 6;
  const int m0 = blockIdx.y * 128;
  const int n0 = blockIdx.x * 128;
  const int srow = lane >> 3;
  const int scol = (lane & 7) * 8;

  f32x4_t acc[4][4] = {};

  const __hip_bfloat16* aptr[4];
  const __hip_bfloat16* bptr[4];
#pragma unroll
  for (int i = 0; i < 4; i++) {
    const int r = (wave * 4 + i) * 8 + srow;
    const int bt = m0 + r;
    const int bb = bt / 63;
    const int tt = bt - bb * 63;
    aptr[i] = WembB + (long)cap[bb * L_ + tt] * 512 + scol;
    bptr[i] = WihB + (long)(n0 + r) * 512 + scol;
  }

  const int wm = (wave >> 1) * 64;
  const int wn = (wave & 1) * 64;
  const int fr = lane & 15;
  const int fk = (lane >> 4) * 8;

  for (int kt = 0; kt < 8; kt++) {
    __syncthreads();
#pragma unroll
    for (int i = 0; i < 4; i++) {
      const int chunk = wave * 4 + i;
      gload_lds16(aptr[i] + kt * 64, sA + chunk * 512);
      gload_lds16(bptr[i] + kt * 64, sB + chunk * 512);
    }
    __syncthreads();
#pragma unroll
    for (int kk = 0; kk < 2; kk++) {
      bf16x8_t a[4], b[4];
#pragma unroll
      for (int i = 0; i < 4; i++) {
        a[i] = lds_frag(sA + (wm + i * 16 + fr) * 64 + kk * 32 + fk);
        b[i] = lds_frag(sB + (wn + i * 16 + fr) * 64 + kk * 32 + fk);
      }
#pragma unroll
      for (int i = 0; i < 4; i++)
#pragma unroll
        for (int j = 0; j < 4; j++)
          acc[i][j] = __builtin_amdgcn_mfma_f32_16x16x32_bf16(a[i], b[j], acc[i][j], 0, 0, 0);
    }
  }

  const int fq = lane >> 4;
#pragma unroll
  for (int j = 0; j < 4; j++) {
    const int n = n0 + wn + j * 16 + fr;
    const float bv = bias[n];
#pragma unroll
    for (int i = 0; i < 4; i++)
#pragma unroll
      for (int rr = 0; rr < 4; rr++) {
        const int m = m0 + wm + i * 16 + fq * 4 + rr;
        C[(long)m * G_ + n] = __float2bfloat16(acc[i][j][rr] + bv);
      }
  }
}

// ---------------- logits GEMM: logits = hs @ W_fc^T + b_fc ----------------
template <bool BBF16>
__global__ __launch_bounds__(256) void GG_gemm_logits(
    const __hip_bfloat16* __restrict__ hfull,  // [B][64][512]
    const void* __restrict__ Bsrc,             // W_fc bf16 or f32 [V][512]
    const float* __restrict__ bias,            // [V] f32
    float* __restrict__ C) {                   // [M][V]
  const int flat = blockIdx.x;
  const int xcd = flat & 7;
  const int s = flat >> 3;           // 0..629
  const int col = xcd * 10 + s % 10; // 0..79
  const int row = s / 10;            // 0..62
  if (col >= 79) return;
  const int m0 = row * 128;
  const int n0 = col * 128;

  __shared__ short sA[128 * 64];
  __shared__ short sB[128 * 64];
  const int lane = threadIdx.x & 63;
  const int wave = threadIdx.x >> 6;
  const int srow = lane >> 3;
  const int scol = (lane & 7) * 8;

  f32x4_t acc[4][4] = {};

  const __hip_bfloat16* aptr[4];
  const __hip_bfloat16* bptrB[4];
  const float* bptrF[4];
#pragma unroll
  for (int i = 0; i < 4; i++) {
    const int r = (wave * 4 + i) * 8 + srow;
    const int m = m0 + r;
    const int bb = m / 63;
    const int tt = m - bb * 63;
    aptr[i] = hfull + ((long)bb * 64 + tt + 1) * 512 + scol;
    int nrow = n0 + r;
    nrow = (nrow < V_) ? nrow : (V_ - 1);
    if constexpr (BBF16) bptrB[i] = (const __hip_bfloat16*)Bsrc + (long)nrow * 512 + scol;
    else                 bptrF[i] = (const float*)Bsrc + (long)nrow * 512 + scol;
  }

  const int wm = (wave >> 1) * 64;
  const int wn = (wave & 1) * 64;
  const int fr = lane & 15;
  const int fk = (lane >> 4) * 8;

  for (int kt = 0; kt < 8; kt++) {
    s16x8_t vb[4];
    if constexpr (!BBF16) {
#pragma unroll
      for (int i = 0; i < 4; i++) vb[i] = cvt8(bptrF[i] + kt * 64);
    }
    __syncthreads();
#pragma unroll
    for (int i = 0; i < 4; i++) {
      const int chunk = wave * 4 + i;
      gload_lds16(aptr[i] + kt * 64, sA + chunk * 512);
      if constexpr (BBF16)
        gload_lds16(bptrB[i] + kt * 64, sB + chunk * 512);
      else
        *reinterpret_cast<s16x8_t*>(sB + chunk * 512 + lane * 8) = vb[i];
    }
    __syncthreads();
#pragma unroll
    for (int kk = 0; kk < 2; kk++) {
      bf16x8_t a[4], b[4];
#pragma unroll
      for (int i = 0; i < 4; i++) {
        a[i] = lds_frag(sA + (wm + i * 16 + fr) * 64 + kk * 32 + fk);
        b[i] = lds_frag(sB + (wn + i * 16 + fr) * 64 + kk * 32 + fk);
      }
#pragma unroll
      for (int i = 0; i < 4; i++)
#pragma unroll
        for (int j = 0; j < 4; j++)
          acc[i][j] = __builtin_amdgcn_mfma_f32_16x16x32_bf16(a[i], b[j], acc[i][j], 0, 0, 0);
    }
  }

  const int fq = lane >> 4;
#pragma unroll
  for (int j = 0; j < 4; j++) {
    const int n = n0 + wn + j * 16 + fr;
    if (n >= V_) continue;
    const float bv = bias[n];
#pragma unroll
    for (int i = 0; i < 4; i++)
#pragma unroll
      for (int rr = 0; rr < 4; rr++) {
        const int m = m0 + wm + i * 16 + fq * 4 + rr;
        C[(long)m * V_ + n] = acc[i][j][rr] + bv;
      }
  }
}

// ---------------- persistent GRU scan, v3 (flag-array barrier) ----------------
// 64 blocks = 2 batch-halves x 32 d-strips. Block: M=64, N=48, K=512.
// Wave w stages only its own 16 batch rows -> no intra-step block barrier for
// staging, single vmcnt(0). Whh strip (48x512) LDS-resident all 63 steps.
// Barrier: per-block RELEASE flag store (no RMW serialization); waiter reads
// all 32 flags with one ACQUIRE vector load per poll + __all ballot.
__global__ __launch_bounds__(256) void GG_scan_persist(
    __hip_bfloat16* __restrict__ hfull,       // [B][64][512]
    const __hip_bfloat16* __restrict__ gi,    // [M][G]
    const __hip_bfloat16* __restrict__ WhhB,  // [G][512] bf16
    const float* __restrict__ bhh,            // [G] f32
    int* __restrict__ flagbase) {
  __shared__ short sW[48 * 512];      // 49,152 B, persistent
  __shared__ short sA[4][16 * 512];   // 65,536 B, per-wave h rows
  const int lane = threadIdx.x & 63;
  const int wave = threadIdx.x >> 6;
  const int strip = blockIdx.x & 31;
  const int half  = blockIdx.x >> 5;
  const int d0 = strip * 16;
  const int fr = lane & 15;
  const int g4 = lane >> 4;            // 0..3
  int* myflags = flagbase + half * 32;

  // one-time: stage Whh strip, XOR-swizzled source granules
  for (int rr = wave; rr < 48; rr += 4) {
    const int grow = (rr >> 4) * 512 + d0 + (rr & 15);
    gload_lds16(WhhB + (long)grow * 512 + (lane ^ (rr & 7)) * 8, sW + rr * 512);
  }

  const int dd = d0 + fr;
  const int bbase = half * 64 + wave * 16 + g4 * 4;  // thread's 4 batch rows
  const float br_ = bhh[dd], bz_ = bhh[512 + dd], bn_ = bhh[1024 + dd];
  const short* gis = (const short*)gi;
  short* sAw = &sA[wave][0];

  // hp registers from h0 (written by prior dispatch)
  float hp[4];
#pragma unroll
  for (int rr = 0; rr < 4; rr++)
    hp[rr] = bf2f(*(const short*)&hfull[((long)(bbase + rr) * 64) * 512 + dd]);

  asm volatile("s_waitcnt vmcnt(0)" ::: "memory");
  __syncthreads();  // sW fully staged (all waves)

  for (int t = 0; t < T_; t++) {
    // gi prefetch (independent of h[t]; hides under barrier spin)
    short gir[4], giz[4], gin[4];
#pragma unroll
    for (int rr = 0; rr < 4; rr++) {
      const long gbase = ((long)(bbase + rr) * T_ + t) * (long)G_;
      gir[rr] = gis[gbase + dd];
      giz[rr] = gis[gbase + 512 + dd];
      gin[rr] = gis[gbase + 1024 + dd];
    }

    if (t > 0) {
      if (threadIdx.x < 64) {  // wave 0 polls; lanes 0..31 read the 32 flags
        while (true) {
          int v = t;
          if (lane < 32)
            v = __hip_atomic_load(&myflags[lane], __ATOMIC_ACQUIRE,
                                  __HIP_MEMORY_SCOPE_AGENT);
          if (__all(v >= t)) break;
          __builtin_amdgcn_s_sleep(4);
        }
      }
      __syncthreads();
    }

    // stage own 16 rows of h[t], full K=512; swizzled source granules
#pragma unroll
    for (int r = 0; r < 16; r++) {
      const int b = half * 64 + wave * 16 + r;
      gload_lds16(hfull + ((long)b * 64 + t) * 512 + (lane ^ (r & 7)) * 8,
                  sAw + r * 512);
    }
    asm volatile("s_waitcnt vmcnt(0)" ::: "memory");
    __builtin_amdgcn_sched_barrier(0);

    f32x4_t acc[3] = {};
#pragma unroll
    for (int kt = 0; kt < 8; kt++)
#pragma unroll
      for (int kk = 0; kk < 2; kk++) {
        const int kg = kt * 8 + kk * 4 + g4;
        const int gsw = (kg ^ (fr & 7)) * 8;
        bf16x8_t afr = lds_frag(sAw + fr * 512 + gsw);
        bf16x8_t bfr[3];
#pragma unroll
        for (int j = 0; j < 3; j++) bfr[j] = lds_frag(sW + (j * 16 + fr) * 512 + gsw);
#pragma unroll
        for (int j = 0; j < 3; j++)
          acc[j] = __builtin_amdgcn_mfma_f32_16x16x32_bf16(afr, bfr[j], acc[j], 0, 0, 0);
      }

    // fused gates; h[t+1] store; hp carried in regs (rounded to stored bf16)
#pragma unroll
    for (int rr = 0; rr < 4; rr++) {
      const float rg = sigmoidf_(bf2f(gir[rr]) + acc[0][rr] + br_);
      const float zg = sigmoidf_(bf2f(giz[rr]) + acc[1][rr] + bz_);
      const float ng = tanhf(bf2f(gin[rr]) + rg * (acc[2][rr] + bn_));
      const short hnb = f2bf((1.f - zg) * ng + zg * hp[rr]);
      hp[rr] = bf2f(hnb);
      *(short*)&hfull[((long)(bbase + rr) * 64 + t + 1) * 512 + dd] = hnb;
    }

    if (t < T_ - 1) {
      __syncthreads();  // all waves' h stores drained before release
      if (threadIdx.x == 0)
        __hip_atomic_store(&myflags[strip], t + 1, __ATOMIC_RELEASE,
                           __HIP_MEMORY_SCOPE_AGENT);
    }
  }
}

// ---------------- tail: out[LOGITS_SZ + b] = f32(len[b] - 1) ----------------
__global__ void GG_tail_kernel(const int* __restrict__ lens, float* __restrict__ out) {
  const int b = threadIdx.x;
  if (b < B_) out[LOGITS_SZ + b] = (float)(lens[b] - 1);
}

extern "C" void kernel_launch(void* const* d_in, const int* in_sizes, int n_in,
                              void* d_out, int out_size, void* d_ws, size_t ws_size,
                              hipStream_t stream) {
  const float* gf      = (const float*)d_in[0];
  const int*   cap     = (const int*)d_in[1];
  const int*   lens    = (const int*)d_in[2];
  const float* W_embed = (const float*)d_in[3];
  const float* W_init  = (const float*)d_in[4];
  const float* b_init  = (const float*)d_in[5];
  const float* W_ih    = (const float*)d_in[6];
  const float* W_hh    = (const float*)d_in[7];
  const float* b_ih    = (const float*)d_in[8];
  const float* b_hh    = (const float*)d_in[9];
  const float* W_fc    = (const float*)d_in[10];
  const float* b_fc    = (const float*)d_in[11];
  float* out = (float*)d_out;

  // d_out scratch (all consumed before the logits GEMM writes d_out):
  char* ob = (char*)d_out;
  __hip_bfloat16* gi_ws  = (__hip_bfloat16*)ob;               // [0, 24,772,608)
  __hip_bfloat16* WhhB   = (__hip_bfloat16*)(ob + 25165824);  // 1.5 MB
  __hip_bfloat16* WihB   = (__hip_bfloat16*)(ob + 27262976);  // 1.5 MB
  __hip_bfloat16* WembB  = (__hip_bfloat16*)(ob + 29360128);  // 10 MB
  __hip_bfloat16* WinitB = (__hip_bfloat16*)(ob + 40894464);  // 2 MB
  __hip_bfloat16* gfB    = (__hip_bfloat16*)(ob + 43253760);  // 0.5 MB

  // ws: hfull [B][64][512] bf16 (slot 0 = h0, slot t+1 = h_t), + WfcB + flags
  __hip_bfloat16* hfull = (__hip_bfloat16*)d_ws;
  __hip_bfloat16* WfcB  = (__hip_bfloat16*)((char*)d_ws + 8388608);
  const bool big_ws = ws_size >= (size_t)(8388608 + 10240000 + 256);
  int* flags = (int*)((char*)d_ws + (big_ws ? 18628608 : 8388608));

  // 0. reset barrier flags (graph-replayed every call -> deterministic)
  hipMemsetAsync(flags, 0, 256, stream);

  // 1. weight/input converts to bf16 (fused: 3908 * 256 covers all 5 segments)
  GG_cvt5<<<dim3(3908), 256, 0, stream>>>(W_hh, WhhB, W_ih, WihB, W_embed, WembB,
                                          W_init, WinitB, gf, gfB);
  if (big_ws)
    GG_cvt_kernel<<<dim3((V_ * D_ / 8 + 255) / 256), 256, 0, stream>>>(W_fc, WfcB, V_ * D_ / 8);

  // 2. h0 -> hfull slot 0 (MFMA GEMM, 4 blocks)
  GG_gemm_h0<<<dim3(4), 256, 0, stream>>>(gfB, WinitB, b_init, hfull);

  // 3. gi = gather(W_embed, cap) @ W_ih^T + b_ih
  GG_gemm_gi<<<dim3(G_ / 128, M_ / 128), 256, 0, stream>>>(WembB, cap, WihB, b_ih, gi_ws);

  // 4. GRU scan: single persistent kernel, 63 steps, flag-array barriers
  GG_scan_persist<<<dim3(SCAN_NB), 256, 0, stream>>>(hfull, gi_ws, WhhB, b_hh, flags);

  // 5. logits (XCD-banded swizzle, 5040 = 8*10*63 padded blocks)
  if (big_ws)
    GG_gemm_logits<true><<<dim3(5040), 256, 0, stream>>>(hfull, WfcB, b_fc, out);
  else
    GG_gemm_logits<false><<<dim3(5040), 256, 0, stream>>>(hfull, W_fc, b_fc, out);

  // 6. second output
  GG_tail_kernel<<<dim3(1), 128, 0, stream>>>(lens, out);
}

// Round 8
// 587.580 us; speedup vs baseline: 5.5599x; 1.0042x over previous
//
#include <hip/hip_runtime.h>
#include <hip/hip_bf16.h>

// Problem dims
#define V_    10000
#define ENC_  2048
#define D_    512
#define B_    128
#define L_    64
#define T_    63          // L-1 timesteps
#define M_    (B_ * L_ - B_)   // 8064 rows (b*63 + t)
#define G_    (3 * D_)    // 1536 gate width
#define LOGITS_SZ ((long)M_ * V_)   // 80,640,000
#define SCAN_NB 64        // 2 batch-halves x 32 d-strips

typedef __bf16 bf16x8_t __attribute__((ext_vector_type(8)));
typedef float  f32x4_t  __attribute__((ext_vector_type(4)));
typedef short  s16x8_t  __attribute__((ext_vector_type(8)));

typedef __attribute__((address_space(3))) char*       lds_cptr_t;
typedef const __attribute__((address_space(1))) char* glb_cptr_t;

// wave-uniform LDS dest; HW writes lane l at dest + l*16B. Global src is per-lane.
__device__ __forceinline__ void gload_lds16(const void* g, void* l) {
  __builtin_amdgcn_global_load_lds((glb_cptr_t)g, (lds_cptr_t)l, 16, 0, 0);
}
__device__ __forceinline__ float bf2f(short s) {
  return __uint_as_float(((unsigned)(unsigned short)s) << 16);
}
__device__ __forceinline__ short f2bf(float f) {
  __hip_bfloat16 h = __float2bfloat16(f);  // RNE
  return *reinterpret_cast<short*>(&h);
}
__device__ __forceinline__ s16x8_t cvt8(const float* p) {
  f32x4_t lo = *reinterpret_cast<const f32x4_t*>(p);
  f32x4_t hi = *reinterpret_cast<const f32x4_t*>(p + 4);
  s16x8_t r;
#pragma unroll
  for (int e = 0; e < 4; e++) { r[e] = f2bf(lo[e]); r[4 + e] = f2bf(hi[e]); }
  return r;
}
__device__ __forceinline__ float sigmoidf_(float x) {
  return 1.0f / (1.0f + __expf(-x));
}
__device__ __forceinline__ bf16x8_t lds_frag(const short* p) {
  return __builtin_bit_cast(bf16x8_t, *reinterpret_cast<const s16x8_t*>(p));
}

// ---------------- fused f32 -> bf16 converts (5 segments, 1 launch) ----------------
__global__ void GG_cvt5(const float* __restrict__ whh, __hip_bfloat16* __restrict__ dwhh,
                        const float* __restrict__ wih, __hip_bfloat16* __restrict__ dwih,
                        const float* __restrict__ wemb, __hip_bfloat16* __restrict__ dwemb,
                        const float* __restrict__ winit, __hip_bfloat16* __restrict__ dwinit,
                        const float* __restrict__ gf, __hip_bfloat16* __restrict__ dgf) {
  const int i = blockIdx.x * blockDim.x + threadIdx.x;
  const float* s; __hip_bfloat16* d; int off;
  if (i < 98304)        { s = whh;   d = dwhh;   off = i; }
  else if (i < 196608)  { s = wih;   d = dwih;   off = i - 98304; }
  else if (i < 836608)  { s = wemb;  d = dwemb;  off = i - 196608; }
  else if (i < 967680)  { s = winit; d = dwinit; off = i - 836608; }
  else                  { s = gf;    d = dgf;    off = i - 967680; }
  s16x8_t v = cvt8(s + (long)off * 8);
  *reinterpret_cast<s16x8_t*>(d + (long)off * 8) = v;
}

__global__ void GG_cvt_kernel(const float* __restrict__ src,
                              __hip_bfloat16* __restrict__ dst, int n8) {
  int i = blockIdx.x * blockDim.x + threadIdx.x;
  if (i < n8) {
    s16x8_t v = cvt8(src + (long)i * 8);
    *reinterpret_cast<s16x8_t*>(dst + (long)i * 8) = v;
  }
}

// ---------------- h0 GEMM: hfull[b][0][:] = tanh(gf @ W_init^T + b_init) ----------------
__global__ __launch_bounds__(256) void GG_gemm_h0(
    const __hip_bfloat16* __restrict__ gfB,     // [128][2048] bf16
    const __hip_bfloat16* __restrict__ WinitB,  // [512][2048] bf16
    const float* __restrict__ binit,            // [512] f32
    __hip_bfloat16* __restrict__ hfull) {       // [B][64][512]
  __shared__ short sA[128 * 64];
  __shared__ short sB[128 * 64];
  const int lane = threadIdx.x & 63;
  const int wave = threadIdx.x >> 6;
  const int n0 = blockIdx.x * 128;
  const int srow = lane >> 3;
  const int scol = (lane & 7) * 8;

  f32x4_t acc[4][4] = {};

  const __hip_bfloat16* aptr[4];
  const __hip_bfloat16* bptr[4];
#pragma unroll
  for (int i = 0; i < 4; i++) {
    const int r = (wave * 4 + i) * 8 + srow;
    aptr[i] = gfB + (long)r * ENC_ + scol;
    bptr[i] = WinitB + (long)(n0 + r) * ENC_ + scol;
  }

  const int wm = (wave >> 1) * 64;
  const int wn = (wave & 1) * 64;
  const int fr = lane & 15;
  const int fk = (lane >> 4) * 8;

  for (int kt = 0; kt < 32; kt++) {
    __syncthreads();
#pragma unroll
    for (int i = 0; i < 4; i++) {
      const int chunk = wave * 4 + i;
      gload_lds16(aptr[i] + kt * 64, sA + chunk * 512);
      gload_lds16(bptr[i] + kt * 64, sB + chunk * 512);
    }
    __syncthreads();
#pragma unroll
    for (int kk = 0; kk < 2; kk++) {
      bf16x8_t a[4], b[4];
#pragma unroll
      for (int i = 0; i < 4; i++) {
        a[i] = lds_frag(sA + (wm + i * 16 + fr) * 64 + kk * 32 + fk);
        b[i] = lds_frag(sB + (wn + i * 16 + fr) * 64 + kk * 32 + fk);
      }
#pragma unroll
      for (int i = 0; i < 4; i++)
#pragma unroll
        for (int j = 0; j < 4; j++)
          acc[i][j] = __builtin_amdgcn_mfma_f32_16x16x32_bf16(a[i], b[j], acc[i][j], 0, 0, 0);
    }
  }

  const int fq = lane >> 4;
#pragma unroll
  for (int j = 0; j < 4; j++) {
    const int n = n0 + wn + j * 16 + fr;
    const float bv = binit[n];
#pragma unroll
    for (int i = 0; i < 4; i++)
#pragma unroll
      for (int rr = 0; rr < 4; rr++) {
        const int m = wm + i * 16 + fq * 4 + rr;
        hfull[(long)m * 64 * 512 + n] = __float2bfloat16(tanhf(acc[i][j][rr] + bv));
      }
  }
}

// ---------------- gi GEMM: gi = gather(W_embed,cap) @ W_ih^T + b_ih ----------------
__global__ __launch_bounds__(256) void GG_gemm_gi(
    const __hip_bfloat16* __restrict__ WembB,  // [V][512] bf16
    const int* __restrict__ cap,               // [B][L] int32
    const __hip_bfloat16* __restrict__ WihB,   // [G][512] bf16
    const float* __restrict__ bias,            // [G] f32
    __hip_bfloat16* __restrict__ C) {          // [M][G]
  __shared__ short sA[128 * 64];
  __shared__ short sB[128 * 64];
  const int lane = threadIdx.x & 63;
  const int wave = threadIdx.x >> 6;
  const int m0 = blockIdx.y * 128;
  const int n0 = blockIdx.x * 128;
  const int srow = lane >> 3;
  const int scol = (lane & 7) * 8;

  f32x4_t acc[4][4] = {};

  const __hip_bfloat16* aptr[4];
  const __hip_bfloat16* bptr[4];
#pragma unroll
  for (int i = 0; i < 4; i++) {
    const int r = (wave * 4 + i) * 8 + srow;
    const int bt = m0 + r;
    const int bb = bt / 63;
    const int tt = bt - bb * 63;
    aptr[i] = WembB + (long)cap[bb * L_ + tt] * 512 + scol;
    bptr[i] = WihB + (long)(n0 + r) * 512 + scol;
  }

  const int wm = (wave >> 1) * 64;
  const int wn = (wave & 1) * 64;
  const int fr = lane & 15;
  const int fk = (lane >> 4) * 8;

  for (int kt = 0; kt < 8; kt++) {
    __syncthreads();
#pragma unroll
    for (int i = 0; i < 4; i++) {
      const int chunk = wave * 4 + i;
      gload_lds16(aptr[i] + kt * 64, sA + chunk * 512);
      gload_lds16(bptr[i] + kt * 64, sB + chunk * 512);
    }
    __syncthreads();
#pragma unroll
    for (int kk = 0; kk < 2; kk++) {
      bf16x8_t a[4], b[4];
#pragma unroll
      for (int i = 0; i < 4; i++) {
        a[i] = lds_frag(sA + (wm + i * 16 + fr) * 64 + kk * 32 + fk);
        b[i] = lds_frag(sB + (wn + i * 16 + fr) * 64 + kk * 32 + fk);
      }
#pragma unroll
      for (int i = 0; i < 4; i++)
#pragma unroll
        for (int j = 0; j < 4; j++)
          acc[i][j] = __builtin_amdgcn_mfma_f32_16x16x32_bf16(a[i], b[j], acc[i][j], 0, 0, 0);
    }
  }

  const int fq = lane >> 4;
#pragma unroll
  for (int j = 0; j < 4; j++) {
    const int n = n0 + wn + j * 16 + fr;
    const float bv = bias[n];
#pragma unroll
    for (int i = 0; i < 4; i++)
#pragma unroll
      for (int rr = 0; rr < 4; rr++) {
        const int m = m0 + wm + i * 16 + fq * 4 + rr;
        C[(long)m * G_ + n] = __float2bfloat16(acc[i][j][rr] + bv);
      }
  }
}

// ---------------- logits GEMM: logits = hs @ W_fc^T + b_fc ----------------
template <bool BBF16>
__global__ __launch_bounds__(256) void GG_gemm_logits(
    const __hip_bfloat16* __restrict__ hfull,  // [B][64][512]
    const void* __restrict__ Bsrc,             // W_fc bf16 or f32 [V][512]
    const float* __restrict__ bias,            // [V] f32
    float* __restrict__ C) {                   // [M][V]
  const int flat = blockIdx.x;
  const int xcd = flat & 7;
  const int s = flat >> 3;           // 0..629
  const int col = xcd * 10 + s % 10; // 0..79
  const int row = s / 10;            // 0..62
  if (col >= 79) return;
  const int m0 = row * 128;
  const int n0 = col * 128;

  __shared__ short sA[128 * 64];
  __shared__ short sB[128 * 64];
  const int lane = threadIdx.x & 63;
  const int wave = threadIdx.x >> 6;
  const int srow = lane >> 3;
  const int scol = (lane & 7) * 8;

  f32x4_t acc[4][4] = {};

  const __hip_bfloat16* aptr[4];
  const __hip_bfloat16* bptrB[4];
  const float* bptrF[4];
#pragma unroll
  for (int i = 0; i < 4; i++) {
    const int r = (wave * 4 + i) * 8 + srow;
    const int m = m0 + r;
    const int bb = m / 63;
    const int tt = m - bb * 63;
    aptr[i] = hfull + ((long)bb * 64 + tt + 1) * 512 + scol;
    int nrow = n0 + r;
    nrow = (nrow < V_) ? nrow : (V_ - 1);
    if constexpr (BBF16) bptrB[i] = (const __hip_bfloat16*)Bsrc + (long)nrow * 512 + scol;
    else                 bptrF[i] = (const float*)Bsrc + (long)nrow * 512 + scol;
  }

  const int wm = (wave >> 1) * 64;
  const int wn = (wave & 1) * 64;
  const int fr = lane & 15;
  const int fk = (lane >> 4) * 8;

  for (int kt = 0; kt < 8; kt++) {
    s16x8_t vb[4];
    if constexpr (!BBF16) {
#pragma unroll
      for (int i = 0; i < 4; i++) vb[i] = cvt8(bptrF[i] + kt * 64);
    }
    __syncthreads();
#pragma unroll
    for (int i = 0; i < 4; i++) {
      const int chunk = wave * 4 + i;
      gload_lds16(aptr[i] + kt * 64, sA + chunk * 512);
      if constexpr (BBF16)
        gload_lds16(bptrB[i] + kt * 64, sB + chunk * 512);
      else
        *reinterpret_cast<s16x8_t*>(sB + chunk * 512 + lane * 8) = vb[i];
    }
    __syncthreads();
#pragma unroll
    for (int kk = 0; kk < 2; kk++) {
      bf16x8_t a[4], b[4];
#pragma unroll
      for (int i = 0; i < 4; i++) {
        a[i] = lds_frag(sA + (wm + i * 16 + fr) * 64 + kk * 32 + fk);
        b[i] = lds_frag(sB + (wn + i * 16 + fr) * 64 + kk * 32 + fk);
      }
#pragma unroll
      for (int i = 0; i < 4; i++)
#pragma unroll
        for (int j = 0; j < 4; j++)
          acc[i][j] = __builtin_amdgcn_mfma_f32_16x16x32_bf16(a[i], b[j], acc[i][j], 0, 0, 0);
    }
  }

  const int fq = lane >> 4;
#pragma unroll
  for (int j = 0; j < 4; j++) {
    const int n = n0 + wn + j * 16 + fr;
    if (n >= V_) continue;
    const float bv = bias[n];
#pragma unroll
    for (int i = 0; i < 4; i++)
#pragma unroll
      for (int rr = 0; rr < 4; rr++) {
        const int m = m0 + wm + i * 16 + fq * 4 + rr;
        C[(long)m * V_ + n] = acc[i][j][rr] + bv;
      }
  }
}

// ---------------- persistent GRU scan, v4 (LLC-coherent exchange) ----------------
// 64 blocks = 2 batch-halves x 32 d-strips. Exchange data (h) and flags use
// sc0+sc1 (bypass L1/L2, served by shared LLC); ordering via vmcnt only.
// No buffer_inv / wbl2 per step -> L2 stays warm for gi/Whh.
// A (h rows) loaded direct-to-register in MFMA fragment layout:
//   lane l: batch row (l&15), k-granule ktile*4 + (l>>4)  [verified layout].
__global__ __launch_bounds__(256) void GG_scan_persist(
    __hip_bfloat16* __restrict__ hfull,       // [B][64][512]
    const __hip_bfloat16* __restrict__ gi,    // [M][G]
    const __hip_bfloat16* __restrict__ WhhB,  // [G][512] bf16
    const float* __restrict__ bhh,            // [G] f32
    int* __restrict__ flagbase) {
  __shared__ short sW[48 * 512];      // 49,152 B, persistent all 63 steps
  const int lane = threadIdx.x & 63;
  const int wave = threadIdx.x >> 6;
  const int strip = blockIdx.x & 31;
  const int half  = blockIdx.x >> 5;
  const int d0 = strip * 16;
  const int fr = lane & 15;
  const int g4 = lane >> 4;            // 0..3
  int* myflags = flagbase + half * 32;

  // one-time: stage Whh strip into LDS (XOR-swizzled source granules)
  for (int rr = wave; rr < 48; rr += 4) {
    const int grow = (rr >> 4) * 512 + d0 + (rr & 15);
    gload_lds16(WhhB + (long)grow * 512 + (lane ^ (rr & 7)) * 8, sW + rr * 512);
  }

  const int dd = d0 + fr;
  const int bbase = half * 64 + wave * 16 + g4 * 4;  // epilogue rows bbase+rr
  const float br_ = bhh[dd], bz_ = bhh[512 + dd], bn_ = bhh[1024 + dd];
  const short* gis = (const short*)gi;

  // A-load base: lane reads batch row (half*64+wave*16+(l&15)), k-offset g4*8
  const int arow = half * 64 + wave * 16 + fr;
  const unsigned long long abase0 =
      (unsigned long long)hfull + ((unsigned long long)arow * 64 * 512 + (unsigned)(g4 * 8)) * 2ull;

  // store bases (4 rows, stride 64KB too big for imm offset)
  unsigned long long sbase[4];
#pragma unroll
  for (int rr = 0; rr < 4; rr++)
    sbase[rr] = (unsigned long long)hfull +
                ((unsigned long long)(bbase + rr) * 64 * 512 + (unsigned)dd) * 2ull;

  // hp registers from h0 (normal cached loads; h0 written by prior dispatch)
  float hp[4];
#pragma unroll
  for (int rr = 0; rr < 4; rr++)
    hp[rr] = bf2f(*(const short*)&hfull[((long)(bbase + rr) * 64) * 512 + dd]);

  asm volatile("s_waitcnt vmcnt(0)" ::: "memory");
  __syncthreads();  // sW fully staged

  for (int t = 0; t < T_; t++) {
    // gi prefetch (normal cached loads; gi is pre-scan constant data)
    short gir[4], giz[4], gin[4];
#pragma unroll
    for (int rr = 0; rr < 4; rr++) {
      const long gbase = ((long)(bbase + rr) * T_ + t) * (long)G_;
      gir[rr] = gis[gbase + dd];
      giz[rr] = gis[gbase + 512 + dd];
      gin[rr] = gis[gbase + 1024 + dd];
    }

    if (t > 0) {
      if (threadIdx.x < 64) {  // wave 0 polls; lanes 0..31 read the 32 flags
        while (true) {
          int v = t;
          if (lane < 32)
            v = __hip_atomic_load(&myflags[lane], __ATOMIC_RELAXED,
                                  __HIP_MEMORY_SCOPE_SYSTEM);
          if (__all(v >= t)) break;
          __builtin_amdgcn_s_sleep(1);
        }
      }
      __syncthreads();
    }

    // direct-to-reg A loads, LLC-coherent (sc0 sc1), 16 K-tiles x 16B/lane
    const unsigned long long ab = abase0 + (unsigned long long)t * 1024ull;
    f32x4_t a[16];
#define ALOAD(IDX, OFF)                                                        \
    asm volatile("global_load_dwordx4 %0, %1, off offset:" #OFF " sc0 sc1"     \
                 : "=v"(a[IDX]) : "v"(ab));
    ALOAD(0, 0)    ALOAD(1, 64)   ALOAD(2, 128)  ALOAD(3, 192)
    ALOAD(4, 256)  ALOAD(5, 320)  ALOAD(6, 384)  ALOAD(7, 448)
    ALOAD(8, 512)  ALOAD(9, 576)  ALOAD(10, 640) ALOAD(11, 704)
    ALOAD(12, 768) ALOAD(13, 832) ALOAD(14, 896) ALOAD(15, 960)
#undef ALOAD
    asm volatile("s_waitcnt vmcnt(0)" ::: "memory");
    __builtin_amdgcn_sched_barrier(0);

    f32x4_t acc[3] = {};
#pragma unroll
    for (int kt = 0; kt < 16; kt++) {
      const bf16x8_t afr = __builtin_bit_cast(bf16x8_t, a[kt]);
      const int gsw = ((kt * 4 + g4) ^ (fr & 7)) * 8;
      bf16x8_t bfr[3];
#pragma unroll
      for (int j = 0; j < 3; j++) bfr[j] = lds_frag(sW + (j * 16 + fr) * 512 + gsw);
#pragma unroll
      for (int j = 0; j < 3; j++)
        acc[j] = __builtin_amdgcn_mfma_f32_16x16x32_bf16(afr, bfr[j], acc[j], 0, 0, 0);
    }

    // fused gates; h[t+1] stored via LLC-coherent shorts; hp carried in regs
#pragma unroll
    for (int rr = 0; rr < 4; rr++) {
      const float rg = sigmoidf_(bf2f(gir[rr]) + acc[0][rr] + br_);
      const float zg = sigmoidf_(bf2f(giz[rr]) + acc[1][rr] + bz_);
      const float ng = tanhf(bf2f(gin[rr]) + rg * (acc[2][rr] + bn_));
      const short hnb = f2bf((1.f - zg) * ng + zg * hp[rr]);
      hp[rr] = bf2f(hnb);
      const unsigned long long saddr = sbase[rr] + (unsigned long long)(t + 1) * 1024ull;
      const unsigned int val = (unsigned short)hnb;
      asm volatile("global_store_short %0, %1, off sc0 sc1"
                   :: "v"(saddr), "v"(val) : "memory");
    }

    if (t < T_ - 1) {
      asm volatile("s_waitcnt vmcnt(0)" ::: "memory");  // stores acked at LLC
      __syncthreads();                                  // whole block done
      if (threadIdx.x == 0)
        __hip_atomic_store(&myflags[strip], t + 1, __ATOMIC_RELAXED,
                           __HIP_MEMORY_SCOPE_SYSTEM);
    }
  }
}

// ---------------- tail: out[LOGITS_SZ + b] = f32(len[b] - 1) ----------------
__global__ void GG_tail_kernel(const int* __restrict__ lens, float* __restrict__ out) {
  const int b = threadIdx.x;
  if (b < B_) out[LOGITS_SZ + b] = (float)(lens[b] - 1);
}

extern "C" void kernel_launch(void* const* d_in, const int* in_sizes, int n_in,
                              void* d_out, int out_size, void* d_ws, size_t ws_size,
                              hipStream_t stream) {
  const float* gf      = (const float*)d_in[0];
  const int*   cap     = (const int*)d_in[1];
  const int*   lens    = (const int*)d_in[2];
  const float* W_embed = (const float*)d_in[3];
  const float* W_init  = (const float*)d_in[4];
  const float* b_init  = (const float*)d_in[5];
  const float* W_ih    = (const float*)d_in[6];
  const float* W_hh    = (const float*)d_in[7];
  const float* b_ih    = (const float*)d_in[8];
  const float* b_hh    = (const float*)d_in[9];
  const float* W_fc    = (const float*)d_in[10];
  const float* b_fc    = (const float*)d_in[11];
  float* out = (float*)d_out;

  // d_out scratch (all consumed before the logits GEMM writes d_out):
  char* ob = (char*)d_out;
  __hip_bfloat16* gi_ws  = (__hip_bfloat16*)ob;               // [0, 24,772,608)
  __hip_bfloat16* WhhB   = (__hip_bfloat16*)(ob + 25165824);  // 1.5 MB
  __hip_bfloat16* WihB   = (__hip_bfloat16*)(ob + 27262976);  // 1.5 MB
  __hip_bfloat16* WembB  = (__hip_bfloat16*)(ob + 29360128);  // 10 MB
  __hip_bfloat16* WinitB = (__hip_bfloat16*)(ob + 40894464);  // 2 MB
  __hip_bfloat16* gfB    = (__hip_bfloat16*)(ob + 43253760);  // 0.5 MB

  // ws: hfull [B][64][512] bf16 (slot 0 = h0, slot t+1 = h_t), + WfcB + flags
  __hip_bfloat16* hfull = (__hip_bfloat16*)d_ws;
  __hip_bfloat16* WfcB  = (__hip_bfloat16*)((char*)d_ws + 8388608);
  const bool big_ws = ws_size >= (size_t)(8388608 + 10240000 + 256);
  int* flags = (int*)((char*)d_ws + (big_ws ? 18628608 : 8388608));

  // 0. reset barrier flags (graph-replayed every call -> deterministic)
  hipMemsetAsync(flags, 0, 256, stream);

  // 1. weight/input converts to bf16 (fused: 3908 * 256 covers all 5 segments)
  GG_cvt5<<<dim3(3908), 256, 0, stream>>>(W_hh, WhhB, W_ih, WihB, W_embed, WembB,
                                          W_init, WinitB, gf, gfB);
  if (big_ws)
    GG_cvt_kernel<<<dim3((V_ * D_ / 8 + 255) / 256), 256, 0, stream>>>(W_fc, WfcB, V_ * D_ / 8);

  // 2. h0 -> hfull slot 0 (MFMA GEMM, 4 blocks)
  GG_gemm_h0<<<dim3(4), 256, 0, stream>>>(gfB, WinitB, b_init, hfull);

  // 3. gi = gather(W_embed, cap) @ W_ih^T + b_ih
  GG_gemm_gi<<<dim3(G_ / 128, M_ / 128), 256, 0, stream>>>(WembB, cap, WihB, b_ih, gi_ws);

  // 4. GRU scan: single persistent kernel, LLC-coherent exchange
  GG_scan_persist<<<dim3(SCAN_NB), 256, 0, stream>>>(hfull, gi_ws, WhhB, b_hh, flags);

  // 5. logits (XCD-banded swizzle, 5040 = 8*10*63 padded blocks)
  if (big_ws)
    GG_gemm_logits<true><<<dim3(5040), 256, 0, stream>>>(hfull, WfcB, b_fc, out);
  else
    GG_gemm_logits<false><<<dim3(5040), 256, 0, stream>>>(hfull, W_fc, b_fc, out);

  // 6. second output
  GG_tail_kernel<<<dim3(1), 128, 0, stream>>>(lens, out);
}

// Round 9
// 558.300 us; speedup vs baseline: 5.8514x; 1.0524x over previous
//
#include <hip/hip_runtime.h>
#include <hip/hip_bf16.h>

// Problem dims
#define V_    10000
#define ENC_  2048
#define D_    512
#define B_    128
#define L_    64
#define T_    63          // L-1 timesteps
#define M_    (B_ * L_ - B_)   // 8064 rows (b*63 + t)
#define G_    (3 * D_)    // 1536 gate width
#define LOGITS_SZ ((long)M_ * V_)   // 80,640,000
#define SCAN_NB 64        // 2 batch-halves x 32 d-strips

typedef __bf16 bf16x8_t __attribute__((ext_vector_type(8)));
typedef float  f32x4_t  __attribute__((ext_vector_type(4)));
typedef short  s16x8_t  __attribute__((ext_vector_type(8)));
typedef unsigned long long ull_t;

typedef __attribute__((address_space(3))) char*       lds_cptr_t;
typedef const __attribute__((address_space(1))) char* glb_cptr_t;

// wave-uniform LDS dest; HW writes lane l at dest + l*16B. Global src is per-lane.
__device__ __forceinline__ void gload_lds16(const void* g, void* l) {
  __builtin_amdgcn_global_load_lds((glb_cptr_t)g, (lds_cptr_t)l, 16, 0, 0);
}
__device__ __forceinline__ float bf2f(short s) {
  return __uint_as_float(((unsigned)(unsigned short)s) << 16);
}
__device__ __forceinline__ short f2bf(float f) {
  __hip_bfloat16 h = __float2bfloat16(f);  // RNE
  return *reinterpret_cast<short*>(&h);
}
__device__ __forceinline__ s16x8_t cvt8(const float* p) {
  f32x4_t lo = *reinterpret_cast<const f32x4_t*>(p);
  f32x4_t hi = *reinterpret_cast<const f32x4_t*>(p + 4);
  s16x8_t r;
#pragma unroll
  for (int e = 0; e < 4; e++) { r[e] = f2bf(lo[e]); r[4 + e] = f2bf(hi[e]); }
  return r;
}
__device__ __forceinline__ float sigmoidf_(float x) {
  return 1.0f / (1.0f + __expf(-x));
}
__device__ __forceinline__ bf16x8_t lds_frag(const short* p) {
  return __builtin_bit_cast(bf16x8_t, *reinterpret_cast<const s16x8_t*>(p));
}

// ---------------- fused f32 -> bf16 converts (5 segments, 1 launch) ----------------
__global__ void GG_cvt5(const float* __restrict__ whh, __hip_bfloat16* __restrict__ dwhh,
                        const float* __restrict__ wih, __hip_bfloat16* __restrict__ dwih,
                        const float* __restrict__ wemb, __hip_bfloat16* __restrict__ dwemb,
                        const float* __restrict__ winit, __hip_bfloat16* __restrict__ dwinit,
                        const float* __restrict__ gf, __hip_bfloat16* __restrict__ dgf) {
  const int i = blockIdx.x * blockDim.x + threadIdx.x;
  const float* s; __hip_bfloat16* d; int off;
  if (i < 98304)        { s = whh;   d = dwhh;   off = i; }
  else if (i < 196608)  { s = wih;   d = dwih;   off = i - 98304; }
  else if (i < 836608)  { s = wemb;  d = dwemb;  off = i - 196608; }
  else if (i < 967680)  { s = winit; d = dwinit; off = i - 836608; }
  else                  { s = gf;    d = dgf;    off = i - 967680; }
  s16x8_t v = cvt8(s + (long)off * 8);
  *reinterpret_cast<s16x8_t*>(d + (long)off * 8) = v;
}

__global__ void GG_cvt_kernel(const float* __restrict__ src,
                              __hip_bfloat16* __restrict__ dst, int n8) {
  int i = blockIdx.x * blockDim.x + threadIdx.x;
  if (i < n8) {
    s16x8_t v = cvt8(src + (long)i * 8);
    *reinterpret_cast<s16x8_t*>(dst + (long)i * 8) = v;
  }
}

// ---------------- h0 GEMM: hfull[b][0][:] = tanh(gf @ W_init^T + b_init) ----------------
__global__ __launch_bounds__(256) void GG_gemm_h0(
    const __hip_bfloat16* __restrict__ gfB,     // [128][2048] bf16
    const __hip_bfloat16* __restrict__ WinitB,  // [512][2048] bf16
    const float* __restrict__ binit,            // [512] f32
    __hip_bfloat16* __restrict__ hfull) {       // [B][64][512]
  __shared__ short sA[128 * 64];
  __shared__ short sB[128 * 64];
  const int lane = threadIdx.x & 63;
  const int wave = threadIdx.x >> 6;
  const int n0 = blockIdx.x * 128;
  const int srow = lane >> 3;
  const int scol = (lane & 7) * 8;

  f32x4_t acc[4][4] = {};

  const __hip_bfloat16* aptr[4];
  const __hip_bfloat16* bptr[4];
#pragma unroll
  for (int i = 0; i < 4; i++) {
    const int r = (wave * 4 + i) * 8 + srow;
    aptr[i] = gfB + (long)r * ENC_ + scol;
    bptr[i] = WinitB + (long)(n0 + r) * ENC_ + scol;
  }

  const int wm = (wave >> 1) * 64;
  const int wn = (wave & 1) * 64;
  const int fr = lane & 15;
  const int fk = (lane >> 4) * 8;

  for (int kt = 0; kt < 32; kt++) {
    __syncthreads();
#pragma unroll
    for (int i = 0; i < 4; i++) {
      const int chunk = wave * 4 + i;
      gload_lds16(aptr[i] + kt * 64, sA + chunk * 512);
      gload_lds16(bptr[i] + kt * 64, sB + chunk * 512);
    }
    __syncthreads();
#pragma unroll
    for (int kk = 0; kk < 2; kk++) {
      bf16x8_t a[4], b[4];
#pragma unroll
      for (int i = 0; i < 4; i++) {
        a[i] = lds_frag(sA + (wm + i * 16 + fr) * 64 + kk * 32 + fk);
        b[i] = lds_frag(sB + (wn + i * 16 + fr) * 64 + kk * 32 + fk);
      }
#pragma unroll
      for (int i = 0; i < 4; i++)
#pragma unroll
        for (int j = 0; j < 4; j++)
          acc[i][j] = __builtin_amdgcn_mfma_f32_16x16x32_bf16(a[i], b[j], acc[i][j], 0, 0, 0);
    }
  }

  const int fq = lane >> 4;
#pragma unroll
  for (int j = 0; j < 4; j++) {
    const int n = n0 + wn + j * 16 + fr;
    const float bv = binit[n];
#pragma unroll
    for (int i = 0; i < 4; i++)
#pragma unroll
      for (int rr = 0; rr < 4; rr++) {
        const int m = wm + i * 16 + fq * 4 + rr;
        hfull[(long)m * 64 * 512 + n] = __float2bfloat16(tanhf(acc[i][j][rr] + bv));
      }
  }
}

// ---------------- gi GEMM: gi = gather(W_embed,cap) @ W_ih^T + b_ih ----------------
__global__ __launch_bounds__(256) void GG_gemm_gi(
    const __hip_bfloat16* __restrict__ WembB,  // [V][512] bf16
    const int* __restrict__ cap,               // [B][L] int32
    const __hip_bfloat16* __restrict__ WihB,   // [G][512] bf16
    const float* __restrict__ bias,            // [G] f32
    __hip_bfloat16* __restrict__ C) {          // [M][G]
  __shared__ short sA[128 * 64];
  __shared__ short sB[128 * 64];
  const int lane = threadIdx.x & 63;
  const int wave = threadIdx.x >> 6;
  const int m0 = blockIdx.y * 128;
  const int n0 = blockIdx.x * 128;
  const int srow = lane >> 3;
  const int scol = (lane & 7) * 8;

  f32x4_t acc[4][4] = {};

  const __hip_bfloat16* aptr[4];
  const __hip_bfloat16* bptr[4];
#pragma unroll
  for (int i = 0; i < 4; i++) {
    const int r = (wave * 4 + i) * 8 + srow;
    const int bt = m0 + r;
    const int bb = bt / 63;
    const int tt = bt - bb * 63;
    aptr[i] = WembB + (long)cap[bb * L_ + tt] * 512 + scol;
    bptr[i] = WihB + (long)(n0 + r) * 512 + scol;
  }

  const int wm = (wave >> 1) * 64;
  const int wn = (wave & 1) * 64;
  const int fr = lane & 15;
  const int fk = (lane >> 4) * 8;

  for (int kt = 0; kt < 8; kt++) {
    __syncthreads();
#pragma unroll
    for (int i = 0; i < 4; i++) {
      const int chunk = wave * 4 + i;
      gload_lds16(aptr[i] + kt * 64, sA + chunk * 512);
      gload_lds16(bptr[i] + kt * 64, sB + chunk * 512);
    }
    __syncthreads();
#pragma unroll
    for (int kk = 0; kk < 2; kk++) {
      bf16x8_t a[4], b[4];
#pragma unroll
      for (int i = 0; i < 4; i++) {
        a[i] = lds_frag(sA + (wm + i * 16 + fr) * 64 + kk * 32 + fk);
        b[i] = lds_frag(sB + (wn + i * 16 + fr) * 64 + kk * 32 + fk);
      }
#pragma unroll
      for (int i = 0; i < 4; i++)
#pragma unroll
        for (int j = 0; j < 4; j++)
          acc[i][j] = __builtin_amdgcn_mfma_f32_16x16x32_bf16(a[i], b[j], acc[i][j], 0, 0, 0);
    }
  }

  const int fq = lane >> 4;
#pragma unroll
  for (int j = 0; j < 4; j++) {
    const int n = n0 + wn + j * 16 + fr;
    const float bv = bias[n];
#pragma unroll
    for (int i = 0; i < 4; i++)
#pragma unroll
      for (int rr = 0; rr < 4; rr++) {
        const int m = m0 + wm + i * 16 + fq * 4 + rr;
        C[(long)m * G_ + n] = __float2bfloat16(acc[i][j][rr] + bv);
      }
  }
}

// ---------------- logits GEMM: logits = hs @ W_fc^T + b_fc ----------------
template <bool BBF16>
__global__ __launch_bounds__(256) void GG_gemm_logits(
    const __hip_bfloat16* __restrict__ hfull,  // [B][64][512]
    const void* __restrict__ Bsrc,             // W_fc bf16 or f32 [V][512]
    const float* __restrict__ bias,            // [V] f32
    float* __restrict__ C) {                   // [M][V]
  const int flat = blockIdx.x;
  const int xcd = flat & 7;
  const int s = flat >> 3;           // 0..629
  const int col = xcd * 10 + s % 10; // 0..79
  const int row = s / 10;            // 0..62
  if (col >= 79) return;
  const int m0 = row * 128;
  const int n0 = col * 128;

  __shared__ short sA[128 * 64];
  __shared__ short sB[128 * 64];
  const int lane = threadIdx.x & 63;
  const int wave = threadIdx.x >> 6;
  const int srow = lane >> 3;
  const int scol = (lane & 7) * 8;

  f32x4_t acc[4][4] = {};

  const __hip_bfloat16* aptr[4];
  const __hip_bfloat16* bptrB[4];
  const float* bptrF[4];
#pragma unroll
  for (int i = 0; i < 4; i++) {
    const int r = (wave * 4 + i) * 8 + srow;
    const int m = m0 + r;
    const int bb = m / 63;
    const int tt = m - bb * 63;
    aptr[i] = hfull + ((long)bb * 64 + tt + 1) * 512 + scol;
    int nrow = n0 + r;
    nrow = (nrow < V_) ? nrow : (V_ - 1);
    if constexpr (BBF16) bptrB[i] = (const __hip_bfloat16*)Bsrc + (long)nrow * 512 + scol;
    else                 bptrF[i] = (const float*)Bsrc + (long)nrow * 512 + scol;
  }

  const int wm = (wave >> 1) * 64;
  const int wn = (wave & 1) * 64;
  const int fr = lane & 15;
  const int fk = (lane >> 4) * 8;

  for (int kt = 0; kt < 8; kt++) {
    s16x8_t vb[4];
    if constexpr (!BBF16) {
#pragma unroll
      for (int i = 0; i < 4; i++) vb[i] = cvt8(bptrF[i] + kt * 64);
    }
    __syncthreads();
#pragma unroll
    for (int i = 0; i < 4; i++) {
      const int chunk = wave * 4 + i;
      gload_lds16(aptr[i] + kt * 64, sA + chunk * 512);
      if constexpr (BBF16)
        gload_lds16(bptrB[i] + kt * 64, sB + chunk * 512);
      else
        *reinterpret_cast<s16x8_t*>(sB + chunk * 512 + lane * 8) = vb[i];
    }
    __syncthreads();
#pragma unroll
    for (int kk = 0; kk < 2; kk++) {
      bf16x8_t a[4], b[4];
#pragma unroll
      for (int i = 0; i < 4; i++) {
        a[i] = lds_frag(sA + (wm + i * 16 + fr) * 64 + kk * 32 + fk);
        b[i] = lds_frag(sB + (wn + i * 16 + fr) * 64 + kk * 32 + fk);
      }
#pragma unroll
      for (int i = 0; i < 4; i++)
#pragma unroll
        for (int j = 0; j < 4; j++)
          acc[i][j] = __builtin_amdgcn_mfma_f32_16x16x32_bf16(a[i], b[j], acc[i][j], 0, 0, 0);
    }
  }

  const int fq = lane >> 4;
#pragma unroll
  for (int j = 0; j < 4; j++) {
    const int n = n0 + wn + j * 16 + fr;
    if (n >= V_) continue;
    const float bv = bias[n];
#pragma unroll
    for (int i = 0; i < 4; i++)
#pragma unroll
      for (int rr = 0; rr < 4; rr++) {
        const int m = m0 + wm + i * 16 + fq * 4 + rr;
        C[(long)m * V_ + n] = acc[i][j][rr] + bv;
      }
  }
}

// ---------------- persistent GRU scan, v5 (clean poll + counted vmcnt) ----------------
// 64 blocks = 2 batch-halves x 32 d-strips. Exchange via LLC (sc0 sc1).
// Per step: poll FIRST with no VMEM outstanding (all 4 waves poll independently),
// then issue 16 A-loads + 12 gi(t+1) prefetch loads (FIFO), s_waitcnt vmcnt(12)
// -> A ready while gi stays in flight. gi(t) consumed from regs (distance-1
// prefetch, rotated after end-of-step vmcnt(0)).
__global__ __launch_bounds__(256) void GG_scan_persist(
    __hip_bfloat16* __restrict__ hfull,       // [B][64][512]
    const __hip_bfloat16* __restrict__ gi,    // [M][G]
    const __hip_bfloat16* __restrict__ WhhB,  // [G][512] bf16
    const float* __restrict__ bhh,            // [G] f32
    int* __restrict__ flagbase) {
  __shared__ short sW[48 * 512];      // 49,152 B, persistent all 63 steps
  const int lane = threadIdx.x & 63;
  const int wave = threadIdx.x >> 6;
  const int strip = blockIdx.x & 31;
  const int half  = blockIdx.x >> 5;
  const int d0 = strip * 16;
  const int fr = lane & 15;
  const int g4 = lane >> 4;            // 0..3
  int* myflags = flagbase + half * 32;

  // one-time: stage Whh strip into LDS (XOR-swizzled source granules)
  for (int rr = wave; rr < 48; rr += 4) {
    const int grow = (rr >> 4) * 512 + d0 + (rr & 15);
    gload_lds16(WhhB + (long)grow * 512 + (lane ^ (rr & 7)) * 8, sW + rr * 512);
  }

  const int dd = d0 + fr;
  const int bbase = half * 64 + wave * 16 + g4 * 4;  // epilogue rows bbase+rr
  const float br_ = bhh[dd], bz_ = bhh[512 + dd], bn_ = bhh[1024 + dd];
  const short* gis = (const short*)gi;

  // A-load base: lane reads batch row (half*64+wave*16+(l&15)), k-offset g4*8
  const int arow = half * 64 + wave * 16 + fr;
  const ull_t abase0 =
      (ull_t)hfull + ((ull_t)arow * 64 * 512 + (unsigned)(g4 * 8)) * 2ull;

  // store bases + gi row bases (element pointers)
  ull_t sbase[4];
  const short* gp0[4];
#pragma unroll
  for (int rr = 0; rr < 4; rr++) {
    sbase[rr] = (ull_t)hfull +
                ((ull_t)(bbase + rr) * 64 * 512 + (unsigned)dd) * 2ull;
    gp0[rr] = gis + (long)(bbase + rr) * T_ * G_ + dd;
  }

  // gi(0) via normal cached loads; hp from h0 slot
  unsigned cr[4], cz[4], cn[4];
  float hp[4];
#pragma unroll
  for (int rr = 0; rr < 4; rr++) {
    cr[rr] = (unsigned short)gp0[rr][0];
    cz[rr] = (unsigned short)gp0[rr][512];
    cn[rr] = (unsigned short)gp0[rr][1024];
    hp[rr] = bf2f(*(const short*)&hfull[((long)(bbase + rr) * 64) * 512 + dd]);
  }

  asm volatile("s_waitcnt vmcnt(0)" ::: "memory");
  __syncthreads();  // sW fully staged

  for (int t = 0; t < T_; t++) {
    // ---- poll (clean: no VMEM outstanding); all 4 waves independently ----
    if (t > 0) {
      while (true) {
        const int v = __hip_atomic_load(&myflags[lane & 31], __ATOMIC_RELAXED,
                                        __HIP_MEMORY_SCOPE_SYSTEM);
        if (__all(v >= t)) break;
        __builtin_amdgcn_s_sleep(1);
      }
    }

    // ---- 16 A-loads, LLC-coherent, direct-to-reg ----
    const ull_t ab = abase0 + (ull_t)t * 1024ull;
    f32x4_t a[16];
#define ALOAD(IDX, OFF)                                                        \
    asm volatile("global_load_dwordx4 %0, %1, off offset:" #OFF " sc0 sc1"     \
                 : "=v"(a[IDX]) : "v"(ab));
    ALOAD(0, 0)    ALOAD(1, 64)   ALOAD(2, 128)  ALOAD(3, 192)
    ALOAD(4, 256)  ALOAD(5, 320)  ALOAD(6, 384)  ALOAD(7, 448)
    ALOAD(8, 512)  ALOAD(9, 576)  ALOAD(10, 640) ALOAD(11, 704)
    ALOAD(12, 768) ALOAD(13, 832) ALOAD(14, 896) ALOAD(15, 960)
#undef ALOAD

    // ---- gi(t+1) prefetch: 12 loads issued AFTER A (FIFO) ----
    const int tp = (t < T_ - 1) ? (t + 1) : (T_ - 1);  // clamped dummy on last
    unsigned nr[4], nz[4], nn[4];
#pragma unroll
    for (int rr = 0; rr < 4; rr++) {
      const short* gp = gp0[rr] + (long)tp * G_;
      asm volatile("global_load_ushort %0, %1, off"             : "=v"(nr[rr]) : "v"(gp));
      asm volatile("global_load_ushort %0, %1, off offset:1024" : "=v"(nz[rr]) : "v"(gp));
      asm volatile("global_load_ushort %0, %1, off offset:2048" : "=v"(nn[rr]) : "v"(gp));
    }

    // A ready; 12 gi loads stay in flight
    asm volatile("s_waitcnt vmcnt(12)" ::: "memory");
    __builtin_amdgcn_sched_barrier(0);

    f32x4_t acc[3] = {};
#pragma unroll
    for (int kt = 0; kt < 16; kt++) {
      const bf16x8_t afr = __builtin_bit_cast(bf16x8_t, a[kt]);
      const int gsw = ((kt * 4 + g4) ^ (fr & 7)) * 8;
      bf16x8_t bfr[3];
#pragma unroll
      for (int j = 0; j < 3; j++) bfr[j] = lds_frag(sW + (j * 16 + fr) * 512 + gsw);
#pragma unroll
      for (int j = 0; j < 3; j++)
        acc[j] = __builtin_amdgcn_mfma_f32_16x16x32_bf16(afr, bfr[j], acc[j], 0, 0, 0);
    }

    // fused gates using gi(t) from regs; h[t+1] stored LLC-coherent
#pragma unroll
    for (int rr = 0; rr < 4; rr++) {
      const float rg = sigmoidf_(bf2f((short)cr[rr]) + acc[0][rr] + br_);
      const float zg = sigmoidf_(bf2f((short)cz[rr]) + acc[1][rr] + bz_);
      const float ng = tanhf(bf2f((short)cn[rr]) + rg * (acc[2][rr] + bn_));
      const short hnb = f2bf((1.f - zg) * ng + zg * hp[rr]);
      hp[rr] = bf2f(hnb);
      const ull_t saddr = sbase[rr] + (ull_t)(t + 1) * 1024ull;
      const unsigned int val = (unsigned short)hnb;
      asm volatile("global_store_short %0, %1, off sc0 sc1"
                   :: "v"(saddr), "v"(val) : "memory");
    }

    // drain stores (and gi prefetch, issued ~a step earlier); then rotate gi regs
    asm volatile("s_waitcnt vmcnt(0)" ::: "memory");
    __builtin_amdgcn_sched_barrier(0);
#pragma unroll
    for (int rr = 0; rr < 4; rr++) { cr[rr] = nr[rr]; cz[rr] = nz[rr]; cn[rr] = nn[rr]; }

    if (t < T_ - 1) {
      __syncthreads();  // whole block's stores drained
      if (threadIdx.x == 0)
        __hip_atomic_store(&myflags[strip], t + 1, __ATOMIC_RELAXED,
                           __HIP_MEMORY_SCOPE_SYSTEM);
    }
  }
}

// ---------------- tail: out[LOGITS_SZ + b] = f32(len[b] - 1) ----------------
__global__ void GG_tail_kernel(const int* __restrict__ lens, float* __restrict__ out) {
  const int b = threadIdx.x;
  if (b < B_) out[LOGITS_SZ + b] = (float)(lens[b] - 1);
}

extern "C" void kernel_launch(void* const* d_in, const int* in_sizes, int n_in,
                              void* d_out, int out_size, void* d_ws, size_t ws_size,
                              hipStream_t stream) {
  const float* gf      = (const float*)d_in[0];
  const int*   cap     = (const int*)d_in[1];
  const int*   lens    = (const int*)d_in[2];
  const float* W_embed = (const float*)d_in[3];
  const float* W_init  = (const float*)d_in[4];
  const float* b_init  = (const float*)d_in[5];
  const float* W_ih    = (const float*)d_in[6];
  const float* W_hh    = (const float*)d_in[7];
  const float* b_ih    = (const float*)d_in[8];
  const float* b_hh    = (const float*)d_in[9];
  const float* W_fc    = (const float*)d_in[10];
  const float* b_fc    = (const float*)d_in[11];
  float* out = (float*)d_out;

  // d_out scratch (all consumed before the logits GEMM writes d_out):
  char* ob = (char*)d_out;
  __hip_bfloat16* gi_ws  = (__hip_bfloat16*)ob;               // [0, 24,772,608)
  __hip_bfloat16* WhhB   = (__hip_bfloat16*)(ob + 25165824);  // 1.5 MB
  __hip_bfloat16* WihB   = (__hip_bfloat16*)(ob + 27262976);  // 1.5 MB
  __hip_bfloat16* WembB  = (__hip_bfloat16*)(ob + 29360128);  // 10 MB
  __hip_bfloat16* WinitB = (__hip_bfloat16*)(ob + 40894464);  // 2 MB
  __hip_bfloat16* gfB    = (__hip_bfloat16*)(ob + 43253760);  // 0.5 MB

  // ws: hfull [B][64][512] bf16 (slot 0 = h0, slot t+1 = h_t), + WfcB + flags
  __hip_bfloat16* hfull = (__hip_bfloat16*)d_ws;
  __hip_bfloat16* WfcB  = (__hip_bfloat16*)((char*)d_ws + 8388608);
  const bool big_ws = ws_size >= (size_t)(8388608 + 10240000 + 256);
  int* flags = (int*)((char*)d_ws + (big_ws ? 18628608 : 8388608));

  // 0. reset barrier flags (graph-replayed every call -> deterministic)
  hipMemsetAsync(flags, 0, 256, stream);

  // 1. weight/input converts to bf16 (fused: 3908 * 256 covers all 5 segments)
  GG_cvt5<<<dim3(3908), 256, 0, stream>>>(W_hh, WhhB, W_ih, WihB, W_embed, WembB,
                                          W_init, WinitB, gf, gfB);
  if (big_ws)
    GG_cvt_kernel<<<dim3((V_ * D_ / 8 + 255) / 256), 256, 0, stream>>>(W_fc, WfcB, V_ * D_ / 8);

  // 2. h0 -> hfull slot 0 (MFMA GEMM, 4 blocks)
  GG_gemm_h0<<<dim3(4), 256, 0, stream>>>(gfB, WinitB, b_init, hfull);

  // 3. gi = gather(W_embed, cap) @ W_ih^T + b_ih
  GG_gemm_gi<<<dim3(G_ / 128, M_ / 128), 256, 0, stream>>>(WembB, cap, WihB, b_ih, gi_ws);

  // 4. GRU scan: single persistent kernel, clean-poll + counted-vmcnt exchange
  GG_scan_persist<<<dim3(SCAN_NB), 256, 0, stream>>>(hfull, gi_ws, WhhB, b_hh, flags);

  // 5. logits (XCD-banded swizzle, 5040 = 8*10*63 padded blocks)
  if (big_ws)
    GG_gemm_logits<true><<<dim3(5040), 256, 0, stream>>>(hfull, WfcB, b_fc, out);
  else
    GG_gemm_logits<false><<<dim3(5040), 256, 0, stream>>>(hfull, W_fc, b_fc, out);

  // 6. second output
  GG_tail_kernel<<<dim3(1), 128, 0, stream>>>(lens, out);
}